// Round 4
// baseline (5678.762 us; speedup 1.0000x reference)
//
#include <hip/hip_runtime.h>
#include <cmath>

#define TPB 256

static constexpr int   Bn   = 8;
static constexpr int   FD   = 128, GD = 128;
static constexpr int   FH   = 64,  FW = 64;
static constexpr int   GH   = 128, GW = 128;
static constexpr int   NPIX = GH * GW;          // 16384
static constexpr long  ROWS = (long)Bn * NPIX;  // 131072
static constexpr int   KIN  = 258, KPAD = 264;
static constexpr int   NH1  = 256, NH2 = 128, NOUT = 33;
static constexpr float TWO_PI = 6.28318530717958647692f;

// ---------------- weight pad: (258x256) -> (264x256) zero-padded rows ----
__global__ __launch_bounds__(TPB)
void k_padw1(const float* __restrict__ w1, float* __restrict__ wp) {
    int i = blockIdx.x * TPB + threadIdx.x;
    if (i >= KPAD * NH1) return;
    int k = i >> 8;                 // row (in_dim index); NH1 == 256
    wp[i] = (k < KIN) ? w1[i] : 0.f;
}

// ---------------- gather metadata per (pixel, offset) -------------------
__global__ __launch_bounds__(TPB)
void k_meta(const float* __restrict__ coord, int* __restrict__ idxb,
            float2* __restrict__ relb) {
    int t = blockIdx.x * TPB + threadIdx.x;
    if (t >= NPIX * 4) return;
    int pix = t >> 2, o = t & 3;
    float cy = coord[pix * 2 + 0], cx = coord[pix * 2 + 1];
    float vx = (o < 2) ? -1.f : 1.f;       // ref loop order: vx outer, vy inner
    float vy = (o & 1) ? 1.f : -1.f;
    float cyo = cy + vx / 64.f, cxo = cx + vy / 64.f;
    float fy = rintf(((cyo + 1.f) * 64.f - 1.f) * 0.5f);
    float fx = rintf(((cxo + 1.f) * 64.f - 1.f) * 0.5f);
    bool valid = (fy >= 0.f) && (fy < 64.f) && (fx >= 0.f) && (fx < 64.f);
    int iy = min(max((int)fy, 0), 63), ix = min(max((int)fx, 0), 63);
    float qcy = valid ? (-1.f + (2.f * iy + 1.f) / 64.f) : 0.f;
    float qcx = valid ? (-1.f + (2.f * ix + 1.f) / 64.f) : 0.f;
    relb[t] = make_float2((cy - qcy) * 64.f, (cx - qcx) * 64.f);
    idxb[t] = valid ? (iy * 64 + ix) : -1;
}

// ---------------- forward DFT, rows pass (real input) --------------------
template <int W>
__global__ __launch_bounds__(TPB)
void k_dft_rows_real(const float* __restrict__ in, float2* __restrict__ out) {
    constexpr int RPB = TPB / W;
    __shared__ float  rowb[RPB][W];
    __shared__ float2 tw[W];
    int t = threadIdx.x;
    int rl = t / W, v = t % W;
    size_t rg = (size_t)blockIdx.x * RPB + rl;
    rowb[rl][v] = in[rg * W + v];
    if (t < W) {
        float s, c; sincosf(-TWO_PI * (float)t / (float)W, &s, &c);
        tw[t] = make_float2(c, s);
    }
    __syncthreads();
    float re = 0.f, im = 0.f;
    #pragma unroll 4
    for (int x = 0; x < W; x++) {
        float a = rowb[rl][x];
        float2 w_ = tw[(v * x) & (W - 1)];
        re = fmaf(a, w_.x, re);
        im = fmaf(a, w_.y, im);
    }
    out[rg * W + v] = make_float2(re, im);
}

// ---------------- forward DFT, cols pass + mag/phase ---------------------
template <int H, int W>
__global__ __launch_bounds__(TPB)
void k_dft_cols_magpha(const float2* __restrict__ in, float* __restrict__ magO,
                       float* __restrict__ phaO) {
    constexpr int VT = 32;
    constexpr int UB = TPB / VT;   // 8
    __shared__ float2 tile[H][VT];
    __shared__ float2 tw[H];
    int t = threadIdx.x;
    int vl = t & (VT - 1), yb = t / VT;
    size_t base = (size_t)blockIdx.x * H * W + (size_t)blockIdx.y * VT;
    for (int y = yb; y < H; y += UB) tile[y][vl] = in[base + (size_t)y * W + vl];
    for (int i = t; i < H; i += TPB) {
        float s, c; sincosf(-TWO_PI * (float)i / (float)H, &s, &c);
        tw[i] = make_float2(c, s);
    }
    __syncthreads();
    for (int u = yb; u < H; u += UB) {
        float re = 0.f, im = 0.f;
        #pragma unroll 4
        for (int y = 0; y < H; y++) {
            float2 d = tile[y][vl];
            float2 w_ = tw[(u * y) & (H - 1)];
            re += d.x * w_.x - d.y * w_.y;
            im += d.x * w_.y + d.y * w_.x;
        }
        size_t oi = base + (size_t)u * W + vl;
        magO[oi] = sqrtf(re * re + im * im);
        phaO[oi] = atan2f(im, re);
    }
}

// ---------------- inverse DFT, rows pass (mag/pha input) -----------------
__global__ __launch_bounds__(TPB)
void k_idft_rows_mp(const float* __restrict__ mag, const float* __restrict__ pha,
                    float2* __restrict__ out) {
    constexpr int W = 128, RPB = 2;
    __shared__ float2 rowb[RPB][W];
    __shared__ float2 tw[W];
    int t = threadIdx.x;
    int rl = t >> 7, v = t & 127;
    size_t rg = (size_t)blockIdx.x * RPB + rl;
    float m = mag[rg * W + v], p = pha[rg * W + v];
    float s, c; sincosf(p, &s, &c);
    rowb[rl][v] = make_float2(m * c, m * s);
    if (t < W) {
        float s2, c2; sincosf(TWO_PI * (float)t / 128.f, &s2, &c2);
        tw[t] = make_float2(c2, s2);
    }
    __syncthreads();
    float re = 0.f, im = 0.f;
    #pragma unroll 4
    for (int x = 0; x < W; x++) {
        float2 d = rowb[rl][x];
        float2 w_ = tw[(v * x) & 127];
        re += d.x * w_.x - d.y * w_.y;
        im += d.x * w_.y + d.y * w_.x;
    }
    out[rg * W + v] = make_float2(re, im);
}

// ---------------- inverse DFT, cols pass + abs + 1/(HW) ------------------
__global__ __launch_bounds__(TPB)
void k_idft_cols_abs(const float2* __restrict__ in, float* __restrict__ out) {
    constexpr int H = 128, W = 128, VT = 32, UB = 8;
    __shared__ float2 tile[H][VT];
    __shared__ float2 tw[H];
    int t = threadIdx.x;
    int vl = t & 31, yb = t >> 5;
    size_t base = (size_t)blockIdx.x * H * W + (size_t)blockIdx.y * VT;
    for (int u = yb; u < H; u += UB) tile[u][vl] = in[base + (size_t)u * W + vl];
    for (int i = t; i < H; i += TPB) {
        float s, c; sincosf(TWO_PI * (float)i / 128.f, &s, &c);
        tw[i] = make_float2(c, s);
    }
    __syncthreads();
    for (int y = yb; y < H; y += UB) {
        float re = 0.f, im = 0.f;
        #pragma unroll 4
        for (int u = 0; u < H; u++) {
            float2 d = tile[u][vl];
            float2 w_ = tw[(y * u) & 127];
            re += d.x * w_.x - d.y * w_.y;
            im += d.x * w_.y + d.y * w_.x;
        }
        out[base + (size_t)y * W + vl] = sqrtf(re * re + im * im) * (1.f / 16384.f);
    }
}

// ---------------- SGEMM (z = offset slice): Cz = act(Az @ B + bias) ------
// 256 threads = 4 waves in a 2x2 wave grid; lanes 8x8 inside a wave.
// RT=BM/16 rows, CT=BN/16 cols per thread. Frag reads are 8-lane broadcast.
template <int BM, int BN, int KTOT, int NACT, bool RELU>
__global__ __launch_bounds__(TPB)
void k_gemm(const float* __restrict__ A, const float* __restrict__ Bw,
            const float* __restrict__ bias, float* __restrict__ C, int chM) {
    constexpr int RT = BM / 16;
    constexpr int CT = BN / 16;
    const float* Az = A + (size_t)blockIdx.z * chM * KTOT;
    float*       Cz = C + (size_t)blockIdx.z * chM * NACT;
    __shared__ float As[8][BM];
    __shared__ float Bs[8][BN];
    int t = threadIdx.x;
    int bm0 = blockIdx.x * BM, bn0 = blockIdx.y * BN;
    int w = t >> 6, l = t & 63;
    int wr = w >> 1, wc = w & 1;
    int tm8 = l >> 3, tn8 = l & 7;
    int fa = wr * (BM / 2) + tm8 * RT;
    int fb = wc * (BN / 2) + tn8 * CT;
    // staging maps
    int am, ak;                       // A: column of k's at row am
    if constexpr (BM == 128) { am = t & 127; ak = (t >> 7) * 4; }
    else                     { am = t & 63;  ak = (t >> 6) * 2; }
    constexpr int BNUM = BN / 32;     // 4 or 2 B floats per thread
    int bk = t >> 5, bn = (t & 31) * BNUM;
    float acc[RT][CT] = {};
    for (int k0 = 0; k0 < KTOT; k0 += 8) {
        float avr[4];
        if constexpr (BM == 128) {
            float4 a4 = *reinterpret_cast<const float4*>(
                &Az[(size_t)(bm0 + am) * KTOT + k0 + ak]);
            avr[0] = a4.x; avr[1] = a4.y; avr[2] = a4.z; avr[3] = a4.w;
        } else {
            float2 a2 = *reinterpret_cast<const float2*>(
                &Az[(size_t)(bm0 + am) * KTOT + k0 + ak]);
            avr[0] = a2.x; avr[1] = a2.y;
        }
        float bvr[BNUM];
        if constexpr ((NACT & 3) == 0 && BNUM == 4) {
            float4 b4 = *reinterpret_cast<const float4*>(
                &Bw[(size_t)(k0 + bk) * NACT + bn0 + bn]);
            bvr[0] = b4.x; bvr[1] = b4.y; bvr[2] = b4.z; bvr[3] = b4.w;
        } else {
            #pragma unroll
            for (int j = 0; j < BNUM; j++) {
                int col = bn0 + bn + j;
                bvr[j] = (col < NACT) ? Bw[(size_t)(k0 + bk) * NACT + col] : 0.f;
            }
        }
        __syncthreads();
        if constexpr (BM == 128) {
            As[ak + 0][am] = avr[0]; As[ak + 1][am] = avr[1];
            As[ak + 2][am] = avr[2]; As[ak + 3][am] = avr[3];
        } else {
            As[ak + 0][am] = avr[0]; As[ak + 1][am] = avr[1];
        }
        #pragma unroll
        for (int j = 0; j < BNUM; j++) Bs[bk][bn + j] = bvr[j];
        __syncthreads();
        #pragma unroll
        for (int kk = 0; kk < 8; kk++) {
            float ar[RT], br[CT];
            #pragma unroll
            for (int i = 0; i < RT; i += 4) {
                float4 a4 = *reinterpret_cast<const float4*>(&As[kk][fa + i]);
                ar[i] = a4.x; ar[i + 1] = a4.y; ar[i + 2] = a4.z; ar[i + 3] = a4.w;
            }
            #pragma unroll
            for (int i = 0; i < CT; i += 4) {
                float4 b4 = *reinterpret_cast<const float4*>(&Bs[kk][fb + i]);
                br[i] = b4.x; br[i + 1] = b4.y; br[i + 2] = b4.z; br[i + 3] = b4.w;
            }
            #pragma unroll
            for (int r = 0; r < RT; r++)
                #pragma unroll
                for (int cc = 0; cc < CT; cc++)
                    acc[r][cc] = fmaf(ar[r], br[cc], acc[r][cc]);
        }
    }
    float bb[CT];
    #pragma unroll
    for (int cc = 0; cc < CT; cc++) {
        int col = bn0 + fb + cc;
        bb[cc] = (col < NACT) ? bias[col] : 0.f;
    }
    #pragma unroll
    for (int r = 0; r < RT; r++) {
        size_t row = bm0 + fa + r;
        if constexpr ((NACT & 3) == 0) {
            #pragma unroll
            for (int i = 0; i < CT; i += 4) {
                float4 o4;
                float* po = (float*)&o4;
                #pragma unroll
                for (int j = 0; j < 4; j++) {
                    float v = acc[r][i + j] + bb[i + j];
                    if (RELU) v = fmaxf(v, 0.f);
                    po[j] = v;
                }
                *reinterpret_cast<float4*>(&Cz[row * NACT + bn0 + fb + i]) = o4;
            }
        } else {
            #pragma unroll
            for (int cc = 0; cc < CT; cc++) {
                int col = bn0 + fb + cc;
                if (col < NACT) {
                    float v = acc[r][cc] + bb[cc];
                    if (RELU) v = fmaxf(v, 0.f);
                    Cz[row * NACT + col] = v;
                }
            }
        }
    }
}

// ---------------- GEMM1 with fused gather A; z = offset ------------------
// BM=128, BN=128, K=264 (258 + zero pad). Writes H1c[z][ch][256].
__global__ __launch_bounds__(TPB)
void k_gemm_gather(const float* __restrict__ featX, const float* __restrict__ guideX,
                   const int* __restrict__ idxb, const float2* __restrict__ relb,
                   int row0, int ch, const float* __restrict__ Bw,
                   const float* __restrict__ bias, float* __restrict__ H1c) {
    __shared__ float As[8][128];
    __shared__ float Bs[8][128];
    __shared__ int sfo[128];
    __shared__ int sgo[128];
    __shared__ float2 srel[128];
    int t = threadIdx.x;
    int o = blockIdx.z;
    int bm0 = blockIdx.x * 128, bn0 = blockIdx.y * 128;
    if (t < 128) {
        int row = row0 + bm0 + t;
        int b = row >> 14, pix = row & 16383;
        int id = idxb[pix * 4 + o];
        sfo[t] = (id >= 0) ? (b * (FD * FH * FW) + id) : -1;
        sgo[t] = b * (GD * GH * GW) + pix;
        srel[t] = relb[pix * 4 + o];
    }
    int w = t >> 6, l = t & 63;
    int wr = w >> 1, wc = w & 1;
    int tm8 = l >> 3, tn8 = l & 7;
    int fa = wr * 64 + tm8 * 8;
    int fb = wc * 64 + tn8 * 8;
    int am = t & 127, kb = (t >> 7) * 4;
    int bk = t >> 5, bn4 = (t & 31) * 4;
    float acc[8][8] = {};
    __syncthreads();
    for (int k0 = 0; k0 < KPAD; k0 += 8) {
        float av[4];
        #pragma unroll
        for (int jl = 0; jl < 4; jl++) {
            int k = k0 + kb + jl;
            float v;
            if (k < 128) {
                int fo = sfo[am];
                v = (fo >= 0) ? featX[(size_t)fo + (size_t)k * (FH * FW)] : 0.f;
            } else if (k < 256) {
                v = guideX[(size_t)sgo[am] + (size_t)(k - 128) * (GH * GW)];
            } else if (k == 256) v = srel[am].x;
            else if (k == 257)   v = srel[am].y;
            else                 v = 0.f;
            av[jl] = v;
        }
        float4 b4 = *reinterpret_cast<const float4*>(
            &Bw[(size_t)(k0 + bk) * NH1 + bn0 + bn4]);
        __syncthreads();
        #pragma unroll
        for (int jl = 0; jl < 4; jl++) As[kb + jl][am] = av[jl];
        *reinterpret_cast<float4*>(&Bs[bk][bn4]) = b4;
        __syncthreads();
        #pragma unroll
        for (int kk = 0; kk < 8; kk++) {
            float4 a0 = *reinterpret_cast<const float4*>(&As[kk][fa]);
            float4 a1 = *reinterpret_cast<const float4*>(&As[kk][fa + 4]);
            float4 b0 = *reinterpret_cast<const float4*>(&Bs[kk][fb]);
            float4 b1 = *reinterpret_cast<const float4*>(&Bs[kk][fb + 4]);
            float ar[8] = {a0.x, a0.y, a0.z, a0.w, a1.x, a1.y, a1.z, a1.w};
            float br[8] = {b0.x, b0.y, b0.z, b0.w, b1.x, b1.y, b1.z, b1.w};
            #pragma unroll
            for (int r = 0; r < 8; r++)
                #pragma unroll
                for (int cc = 0; cc < 8; cc++)
                    acc[r][cc] = fmaf(ar[r], br[cc], acc[r][cc]);
        }
    }
    float bb[8];
    #pragma unroll
    for (int cc = 0; cc < 8; cc++) bb[cc] = bias[bn0 + fb + cc];
    #pragma unroll
    for (int r = 0; r < 8; r++) {
        size_t row = (size_t)o * ch + bm0 + fa + r;
        float4 o4a, o4b;
        float* pa = (float*)&o4a; float* pb = (float*)&o4b;
        #pragma unroll
        for (int cc = 0; cc < 4; cc++) {
            pa[cc] = fmaxf(acc[r][cc] + bb[cc], 0.f);
            pb[cc] = fmaxf(acc[r][cc + 4] + bb[cc + 4], 0.f);
        }
        *reinterpret_cast<float4*>(&H1c[row * NH1 + bn0 + fb]) = o4a;
        *reinterpret_cast<float4*>(&H1c[row * NH1 + bn0 + fb + 4]) = o4b;
    }
}

// ---------------- softmax over 4 offsets + weighted sum (per chunk) ------
__global__ __launch_bounds__(TPB)
void k_combine(const float* __restrict__ predsC, int row0, int ch,
               float* __restrict__ res) {
    int rl_ = blockIdx.x * TPB + threadIdx.x;
    if (rl_ >= ch) return;
    float p3[4];
    #pragma unroll
    for (int o = 0; o < 4; o++)
        p3[o] = predsC[((size_t)o * ch + rl_) * NOUT + 32];
    float mx = fmaxf(fmaxf(p3[0], p3[1]), fmaxf(p3[2], p3[3]));
    float e[4], sum = 0.f;
    #pragma unroll
    for (int o = 0; o < 4; o++) { e[o] = expf(p3[o] - mx); sum += e[o]; }
    float inv = 1.f / sum;
    int row = row0 + rl_;
    int b = row >> 14, pix = row & 16383;
    float* outb = res + (size_t)b * 32 * NPIX + pix;
    for (int c = 0; c < 32; c++) {
        float acc = 0.f;
        #pragma unroll
        for (int o = 0; o < 4; o++)
            acc = fmaf(predsC[((size_t)o * ch + rl_) * NOUT + c], e[o] * inv, acc);
        outb[(size_t)c * NPIX] = acc;
    }
}

// =========================================================================
static size_t align256(size_t x) { return (x + 255) & ~(size_t)255; }

static size_t plan_bytes(int ch) {
    // scratch region: MLP chunk buffers, but at least 32 MiB for FFT temps
    size_t region = align256((size_t)ch * 4 * NH1 * 4)
                  + align256((size_t)ch * 4 * NH2 * 4)
                  + align256((size_t)ch * 4 * NOUT * 4);
    if (region < 33554432) region = 33554432;
    size_t t = align256(region);
    t += align256((size_t)Bn * FD * FH * FW * 4) * 2;   // featM, featP
    t += align256((size_t)Bn * GD * GH * GW * 4) * 2;   // guideM, guideP
    t += align256((size_t)Bn * 32 * NPIX * 4);          // phares (magres = d_out)
    t += align256((size_t)KPAD * NH1 * 4) * 2;          // w1 pads
    t += align256((size_t)NPIX * 4 * 4);                // idxb
    t += align256((size_t)NPIX * 4 * 8);                // relb
    return t;
}

extern "C" void kernel_launch(void* const* d_in, const int* in_sizes, int n_in,
                              void* d_out, int out_size, void* d_ws, size_t ws_size,
                              hipStream_t stream) {
    const float* feat  = (const float*)d_in[0];
    const float* coord = (const float*)d_in[1];
    const float* guide = (const float*)d_in[2];
    const float* aw1 = (const float*)d_in[3];
    const float* ab1 = (const float*)d_in[4];
    const float* aw2 = (const float*)d_in[5];
    const float* ab2 = (const float*)d_in[6];
    const float* aw3 = (const float*)d_in[7];
    const float* ab3 = (const float*)d_in[8];
    const float* pw1 = (const float*)d_in[9];
    const float* pb1 = (const float*)d_in[10];
    const float* pw2 = (const float*)d_in[11];
    const float* pb2 = (const float*)d_in[12];
    const float* pw3 = (const float*)d_in[13];
    const float* pb3 = (const float*)d_in[14];
    float* out = (float*)d_out;

    // pick the largest chunk that fits the workspace (deterministic per run)
    int ch = 0;
    const int cands[3] = {16384, 8192, 4096};
    for (int i = 0; i < 3; i++)
        if (plan_bytes(cands[i]) <= ws_size) { ch = cands[i]; break; }
    if (ch == 0) return;   // diagnostic: output stays poisoned, no fault
    const int nchk = (int)(ROWS / ch);

    char* ws = (char*)d_ws;
    size_t off = 0;
    auto alloc = [&](size_t bytes) -> void* {
        void* p = ws + off;
        off += align256(bytes);
        return p;
    };
    size_t region = align256((size_t)ch * 4 * NH1 * 4)
                  + align256((size_t)ch * 4 * NH2 * 4)
                  + align256((size_t)ch * 4 * NOUT * 4);
    if (region < 33554432) region = 33554432;
    // region: FFT complex temps AND (disjoint lifetime) H1c/H2c/predsC
    char*   rbase  = (char*)alloc(region);
    float2* R0c    = (float2*)rbase;
    float*  H1c    = (float*)rbase;
    float*  H2c    = (float*)(rbase + align256((size_t)ch * 4 * NH1 * 4));
    float*  predsC = (float*)(rbase + align256((size_t)ch * 4 * NH1 * 4)
                                    + align256((size_t)ch * 4 * NH2 * 4));
    float*  featM  = (float*)alloc((size_t)Bn * FD * FH * FW * 4);   // 16 MiB
    float*  featP  = (float*)alloc((size_t)Bn * FD * FH * FW * 4);   // 16 MiB
    float*  guideM = (float*)alloc((size_t)Bn * GD * GH * GW * 4);   // 64 MiB
    float*  guideP = (float*)alloc((size_t)Bn * GD * GH * GW * 4);   // 64 MiB
    float*  phares = (float*)alloc((size_t)Bn * 32 * NPIX * 4);      // 16 MiB
    float*  magres = out;   // alias: consumed by iFFT rows before out written
    float*  w1pa   = (float*)alloc((size_t)KPAD * NH1 * 4);
    float*  w1pp   = (float*)alloc((size_t)KPAD * NH1 * 4);
    int*    idxb   = (int*)alloc((size_t)NPIX * 4 * 4);
    float2* relb   = (float2*)alloc((size_t)NPIX * 4 * 8);

    // ---- prep
    k_padw1<<<(KPAD * NH1 + TPB - 1) / TPB, TPB, 0, stream>>>(aw1, w1pa);
    k_padw1<<<(KPAD * NH1 + TPB - 1) / TPB, TPB, 0, stream>>>(pw1, w1pp);
    k_meta<<<(NPIX * 4 + TPB - 1) / TPB, TPB, 0, stream>>>(coord, idxb, relb);

    // ---- forward FFT: feat (1024 imgs 64x64) — temp 32 MiB, single shot
    k_dft_rows_real<64><<<(Bn * FD * FH) / 4, TPB, 0, stream>>>(feat, R0c);
    k_dft_cols_magpha<64, 64><<<dim3(Bn * FD, FW / 32), TPB, 0, stream>>>(R0c, featM, featP);
    // ---- forward FFT: guide (1024 imgs 128x128) — 4 chunks of 256 imgs
    for (int g = 0; g < 4; g++) {
        const float* gin = guide + (size_t)g * 256 * NPIX;
        k_dft_rows_real<128><<<(256 * GH) / 2, TPB, 0, stream>>>(gin, R0c);
        k_dft_cols_magpha<128, 128><<<dim3(256, GW / 32), TPB, 0, stream>>>(
            R0c, guideM + (size_t)g * 256 * NPIX, guideP + (size_t)g * 256 * NPIX);
    }

    // ---- two MLP branches (mag with a_*, pha with p_*), row-chunked
    for (int br = 0; br < 2; br++) {
        const float* fX  = br ? featP  : featM;
        const float* gX  = br ? guideP : guideM;
        const float* w1p = br ? w1pp : w1pa;
        const float* b1  = br ? pb1  : ab1;
        const float* w2  = br ? pw2  : aw2;
        const float* b2  = br ? pb2  : ab2;
        const float* w3  = br ? pw3  : aw3;
        const float* b3  = br ? pb3  : ab3;
        float* resb = br ? phares : magres;
        for (int c = 0; c < nchk; c++) {
            int row0 = c * ch;
            k_gemm_gather<<<dim3(ch / 128, NH1 / 128, 4), TPB, 0, stream>>>(
                fX, gX, idxb, relb, row0, ch, w1p, b1, H1c);
            k_gemm<64, 128, 256, 128, true><<<dim3(ch / 64, 1, 4), TPB, 0, stream>>>(
                H1c, w2, b2, H2c, ch);
            k_gemm<64, 64, 128, 33, false><<<dim3(ch / 64, 1, 4), TPB, 0, stream>>>(
                H2c, w3, b3, predsC, ch);
            k_combine<<<ch / TPB, TPB, 0, stream>>>(predsC, row0, ch, resb);
        }
    }

    // ---- inverse FFT (256 imgs 128x128) + abs — temp 32 MiB, single shot
    k_idft_rows_mp<<<(Bn * 32 * GH) / 2, TPB, 0, stream>>>(magres, phares, R0c);
    k_idft_cols_abs<<<dim3(Bn * 32, GW / 32), TPB, 0, stream>>>(R0c, out);
}

// Round 5
// 3981.346 us; speedup vs baseline: 1.4263x; 1.4263x over previous
//
#include <hip/hip_runtime.h>
#include <cmath>

#define TPB 256

static constexpr int   Bn   = 8;
static constexpr int   FD   = 128, GD = 128;
static constexpr int   FH   = 64,  FW = 64;
static constexpr int   GH   = 128, GW = 128;
static constexpr int   NPIX = GH * GW;          // 16384
static constexpr long  ROWS = (long)Bn * NPIX;  // 131072
static constexpr int   NH1  = 256, NH2 = 128, NOUT = 33;
static constexpr float TWO_PI = 6.28318530717958647692f;

typedef __attribute__((ext_vector_type(8))) __bf16 bf16x8;
typedef __attribute__((ext_vector_type(4))) float  f32x4;

// ---------------- gather metadata per (pixel, offset) -------------------
__global__ __launch_bounds__(TPB)
void k_meta(const float* __restrict__ coord, int* __restrict__ idxb,
            float2* __restrict__ relb) {
    int t = blockIdx.x * TPB + threadIdx.x;
    if (t >= NPIX * 4) return;
    int pix = t >> 2, o = t & 3;
    float cy = coord[pix * 2 + 0], cx = coord[pix * 2 + 1];
    float vx = (o < 2) ? -1.f : 1.f;       // ref loop order: vx outer, vy inner
    float vy = (o & 1) ? 1.f : -1.f;
    float cyo = cy + vx / 64.f, cxo = cx + vy / 64.f;
    float fy = rintf(((cyo + 1.f) * 64.f - 1.f) * 0.5f);
    float fx = rintf(((cxo + 1.f) * 64.f - 1.f) * 0.5f);
    bool valid = (fy >= 0.f) && (fy < 64.f) && (fx >= 0.f) && (fx < 64.f);
    int iy = min(max((int)fy, 0), 63), ix = min(max((int)fx, 0), 63);
    float qcy = valid ? (-1.f + (2.f * iy + 1.f) / 64.f) : 0.f;
    float qcx = valid ? (-1.f + (2.f * ix + 1.f) / 64.f) : 0.f;
    relb[t] = make_float2((cy - qcy) * 64.f, (cx - qcx) * 64.f);
    idxb[t] = valid ? (iy * 64 + ix) : -1;
}

// ---------------- weight prep: split-bf16 + MFMA-layout transpose --------
// w1 (258x256) -> w1t [nb 2][step 8][h 2][kb 4][nl 128][j 8] bf16, plus
// relw[n] = (w1[256][n], w1[257][n]).
__global__ __launch_bounds__(TPB)
void k_prep_w1(const float* __restrict__ w1, __bf16* __restrict__ w1t,
               float2* __restrict__ relw) {
    int i = blockIdx.x * TPB + threadIdx.x;
    if (i < 256) relw[i] = make_float2(w1[256 * 256 + i], w1[257 * 256 + i]);
    if (i >= 256 * 256) return;
    int k = i >> 8, n = i & 255;
    float v = w1[k * 256 + n];
    __bf16 h = (__bf16)v;
    __bf16 lo = (__bf16)(v - (float)h);
    int nb = n >> 7, nl = n & 127, st = k >> 5, kb = (k >> 3) & 3, j = k & 7;
    size_t slab = ((size_t)nb * 8 + st) * 8192;
    w1t[slab + 0    + kb * 1024 + nl * 8 + j] = h;
    w1t[slab + 4096 + kb * 1024 + nl * 8 + j] = lo;
}

// w2 (256x128) -> w2t [step 8][h 2][kb 4][n 128][j 8]
__global__ __launch_bounds__(TPB)
void k_prep_w2(const float* __restrict__ w2, __bf16* __restrict__ w2t) {
    int i = blockIdx.x * TPB + threadIdx.x;
    if (i >= 256 * 128) return;
    int k = i >> 7, n = i & 127;
    float v = w2[k * 128 + n];
    __bf16 h = (__bf16)v;
    __bf16 lo = (__bf16)(v - (float)h);
    int st = k >> 5, kb = (k >> 3) & 3, j = k & 7;
    size_t slab = (size_t)st * 8192;
    w2t[slab + 0    + kb * 1024 + n * 8 + j] = h;
    w2t[slab + 4096 + kb * 1024 + n * 8 + j] = lo;
}

// ---------------- forward DFT, rows pass (real input) --------------------
template <int W>
__global__ __launch_bounds__(TPB)
void k_dft_rows_real(const float* __restrict__ in, float2* __restrict__ out) {
    constexpr int RPB = TPB / W;
    __shared__ float  rowb[RPB][W];
    __shared__ float2 tw[W];
    int t = threadIdx.x;
    int rl = t / W, v = t % W;
    size_t rg = (size_t)blockIdx.x * RPB + rl;
    rowb[rl][v] = in[rg * W + v];
    if (t < W) {
        float s, c; sincosf(-TWO_PI * (float)t / (float)W, &s, &c);
        tw[t] = make_float2(c, s);
    }
    __syncthreads();
    float re = 0.f, im = 0.f;
    #pragma unroll 4
    for (int x = 0; x < W; x++) {
        float a = rowb[rl][x];
        float2 w_ = tw[(v * x) & (W - 1)];
        re = fmaf(a, w_.x, re);
        im = fmaf(a, w_.y, im);
    }
    out[rg * W + v] = make_float2(re, im);
}

// ---------------- forward DFT, cols pass + mag/phase ---------------------
template <int H, int W>
__global__ __launch_bounds__(TPB)
void k_dft_cols_magpha(const float2* __restrict__ in, float* __restrict__ magO,
                       float* __restrict__ phaO) {
    constexpr int VT = 32;
    constexpr int UB = TPB / VT;   // 8
    __shared__ float2 tile[H][VT];
    __shared__ float2 tw[H];
    int t = threadIdx.x;
    int vl = t & (VT - 1), yb = t / VT;
    size_t base = (size_t)blockIdx.x * H * W + (size_t)blockIdx.y * VT;
    for (int y = yb; y < H; y += UB) tile[y][vl] = in[base + (size_t)y * W + vl];
    for (int i = t; i < H; i += TPB) {
        float s, c; sincosf(-TWO_PI * (float)i / (float)H, &s, &c);
        tw[i] = make_float2(c, s);
    }
    __syncthreads();
    for (int u = yb; u < H; u += UB) {
        float re = 0.f, im = 0.f;
        #pragma unroll 4
        for (int y = 0; y < H; y++) {
            float2 d = tile[y][vl];
            float2 w_ = tw[(u * y) & (H - 1)];
            re += d.x * w_.x - d.y * w_.y;
            im += d.x * w_.y + d.y * w_.x;
        }
        size_t oi = base + (size_t)u * W + vl;
        magO[oi] = sqrtf(re * re + im * im);
        phaO[oi] = atan2f(im, re);
    }
}

// ---------------- inverse DFT, rows pass (mag/pha input) -----------------
__global__ __launch_bounds__(TPB)
void k_idft_rows_mp(const float* __restrict__ mag, const float* __restrict__ pha,
                    float2* __restrict__ out) {
    constexpr int W = 128, RPB = 2;
    __shared__ float2 rowb[RPB][W];
    __shared__ float2 tw[W];
    int t = threadIdx.x;
    int rl = t >> 7, v = t & 127;
    size_t rg = (size_t)blockIdx.x * RPB + rl;
    float m = mag[rg * W + v], p = pha[rg * W + v];
    float s, c; sincosf(p, &s, &c);
    rowb[rl][v] = make_float2(m * c, m * s);
    if (t < W) {
        float s2, c2; sincosf(TWO_PI * (float)t / 128.f, &s2, &c2);
        tw[t] = make_float2(c2, s2);
    }
    __syncthreads();
    float re = 0.f, im = 0.f;
    #pragma unroll 4
    for (int x = 0; x < W; x++) {
        float2 d = rowb[rl][x];
        float2 w_ = tw[(v * x) & 127];
        re += d.x * w_.x - d.y * w_.y;
        im += d.x * w_.y + d.y * w_.x;
    }
    out[rg * W + v] = make_float2(re, im);
}

// ---------------- inverse DFT, cols pass + abs + 1/(HW) ------------------
__global__ __launch_bounds__(TPB)
void k_idft_cols_abs(const float2* __restrict__ in, float* __restrict__ out) {
    constexpr int H = 128, W = 128, VT = 32, UB = 8;
    __shared__ float2 tile[H][VT];
    __shared__ float2 tw[H];
    int t = threadIdx.x;
    int vl = t & 31, yb = t >> 5;
    size_t base = (size_t)blockIdx.x * H * W + (size_t)blockIdx.y * VT;
    for (int u = yb; u < H; u += UB) tile[u][vl] = in[base + (size_t)u * W + vl];
    for (int i = t; i < H; i += TPB) {
        float s, c; sincosf(TWO_PI * (float)i / 128.f, &s, &c);
        tw[i] = make_float2(c, s);
    }
    __syncthreads();
    for (int y = yb; y < H; y += UB) {
        float re = 0.f, im = 0.f;
        #pragma unroll 4
        for (int u = 0; u < H; u++) {
            float2 d = tile[u][vl];
            float2 w_ = tw[(y * u) & 127];
            re += d.x * w_.x - d.y * w_.y;
            im += d.x * w_.y + d.y * w_.x;
        }
        out[base + (size_t)y * W + vl] = sqrtf(re * re + im * im) * (1.f / 16384.f);
    }
}

// ---------------- GEMM1: gather + split-bf16 MFMA ------------------------
// C(128x128 per block) = relu(A(gathered, K=256) @ W1 + b1 + rel-rank2).
// LDS tiles [h][kb][m][8k]; frags: A row=l&15 k=(l>>4)*8+j; C col=l&15,
// row=(l>>4)*4+reg (HW-verified layouts).
__global__ __launch_bounds__(TPB)
void k_gemm1_mfma(const float* __restrict__ featX, const float* __restrict__ guideX,
                  const int* __restrict__ idxb, const float2* __restrict__ relb,
                  int row0, int ch, const __bf16* __restrict__ w1t,
                  const float2* __restrict__ relw, const float* __restrict__ b1,
                  float* __restrict__ H1c) {
    __shared__ __align__(16) __bf16 As2[2][4][128][8];
    __shared__ __align__(16) __bf16 Bs2[8192];
    __shared__ int    sfo[128];
    __shared__ int    sgo[128];
    __shared__ float2 srel[128];
    int t = threadIdx.x;
    int o = blockIdx.z;
    int bm0 = blockIdx.x * 128;
    int nb  = blockIdx.y;
    int bn0 = nb * 128;
    if (t < 128) {
        int row = row0 + bm0 + t;
        int b = row >> 14, pix = row & 16383;
        int id = idxb[pix * 4 + o];
        sfo[t] = (id >= 0) ? (b * (FD * FH * FW) + id) : -1;
        sgo[t] = b * (GD * GH * GW) + pix;
        srel[t] = relb[pix * 4 + o];
    }
    int w = t >> 6, l = t & 63;
    int wr = w >> 1, wc = w & 1;
    int lr = l & 15, lk = l >> 4;
    int am = t >> 1, kh = t & 1;
    const __bf16* wbase = w1t + (size_t)nb * 65536;
    f32x4 acc[4][4];
    #pragma unroll
    for (int i = 0; i < 4; i++)
        #pragma unroll
        for (int j = 0; j < 4; j++) acc[i][j] = f32x4{0.f, 0.f, 0.f, 0.f};
    __syncthreads();   // sfo/sgo/srel ready
    for (int st = 0; st < 8; st++) {
        int k0 = st * 32;
        // global -> regs
        float va[16];
        if (st < 4) {
            int fo = sfo[am];
            int kbase = k0 + kh * 16;
            if (fo >= 0) {
                #pragma unroll
                for (int j = 0; j < 16; j++)
                    va[j] = featX[(size_t)fo + (size_t)(kbase + j) * (FH * FW)];
            } else {
                #pragma unroll
                for (int j = 0; j < 16; j++) va[j] = 0.f;
            }
        } else {
            int go = sgo[am];
            int kbase = k0 - 128 + kh * 16;
            #pragma unroll
            for (int j = 0; j < 16; j++)
                va[j] = guideX[(size_t)go + (size_t)(kbase + j) * (GH * GW)];
        }
        float4 bv[4];
        const float4* wsl = (const float4*)(wbase + (size_t)st * 8192);
        #pragma unroll
        for (int i = 0; i < 4; i++) bv[i] = wsl[i * 256 + t];
        __syncthreads();   // previous compute done with LDS
        {
            __bf16 h8[16], l8[16];
            #pragma unroll
            for (int j = 0; j < 16; j++) {
                __bf16 h = (__bf16)va[j];
                h8[j] = h;
                l8[j] = (__bf16)(va[j] - (float)h);
            }
            int kb0 = kh * 2;
            *(bf16x8*)&As2[0][kb0][am][0]     = *(bf16x8*)&h8[0];
            *(bf16x8*)&As2[0][kb0 + 1][am][0] = *(bf16x8*)&h8[8];
            *(bf16x8*)&As2[1][kb0][am][0]     = *(bf16x8*)&l8[0];
            *(bf16x8*)&As2[1][kb0 + 1][am][0] = *(bf16x8*)&l8[8];
            float4* bd = (float4*)&Bs2[0];
            #pragma unroll
            for (int i = 0; i < 4; i++) bd[i * 256 + t] = bv[i];
        }
        __syncthreads();
        bf16x8 ah[4], al[4], bh[4], blo[4];
        #pragma unroll
        for (int mf = 0; mf < 4; mf++) {
            int m = wr * 64 + mf * 16 + lr;
            ah[mf] = *(const bf16x8*)&As2[0][lk][m][0];
            al[mf] = *(const bf16x8*)&As2[1][lk][m][0];
        }
        #pragma unroll
        for (int nf = 0; nf < 4; nf++) {
            int n = wc * 64 + nf * 16 + lr;
            bh[nf]  = *(const bf16x8*)&Bs2[(size_t)lk * 1024 + n * 8];
            blo[nf] = *(const bf16x8*)&Bs2[4096 + (size_t)lk * 1024 + n * 8];
        }
        #pragma unroll
        for (int mf = 0; mf < 4; mf++)
            #pragma unroll
            for (int nf = 0; nf < 4; nf++) {
                acc[mf][nf] = __builtin_amdgcn_mfma_f32_16x16x32_bf16(ah[mf], bh[nf],  acc[mf][nf], 0, 0, 0);
                acc[mf][nf] = __builtin_amdgcn_mfma_f32_16x16x32_bf16(ah[mf], blo[nf], acc[mf][nf], 0, 0, 0);
                acc[mf][nf] = __builtin_amdgcn_mfma_f32_16x16x32_bf16(al[mf], bh[nf],  acc[mf][nf], 0, 0, 0);
            }
    }
    // epilogue: bias + rel rank-2 + relu
    #pragma unroll
    for (int nf = 0; nf < 4; nf++) {
        int col = bn0 + wc * 64 + nf * 16 + lr;
        float bias = b1[col];
        float2 rw = relw[col];
        #pragma unroll
        for (int mf = 0; mf < 4; mf++)
            #pragma unroll
            for (int r = 0; r < 4; r++) {
                int rloc = wr * 64 + mf * 16 + lk * 4 + r;
                float2 rr = srel[rloc];
                float v = acc[mf][nf][r] + bias + rr.x * rw.x + rr.y * rw.y;
                H1c[((size_t)o * ch + bm0 + rloc) * NH1 + col] = fmaxf(v, 0.f);
            }
    }
}

// ---------------- GEMM2: H1 (fp32) x W2, split-bf16 MFMA -----------------
__global__ __launch_bounds__(TPB)
void k_gemm2_mfma(const float* __restrict__ A, const __bf16* __restrict__ w2t,
                  const float* __restrict__ b2, float* __restrict__ H2c, int ch) {
    __shared__ __align__(16) __bf16 As2[2][4][128][8];
    __shared__ __align__(16) __bf16 Bs2[8192];
    int t = threadIdx.x;
    int o = blockIdx.z;
    int bm0 = blockIdx.x * 128;
    int w = t >> 6, l = t & 63;
    int wr = w >> 1, wc = w & 1;
    int lr = l & 15, lk = l >> 4;
    int am = t >> 1, kh = t & 1;
    f32x4 acc[4][4];
    #pragma unroll
    for (int i = 0; i < 4; i++)
        #pragma unroll
        for (int j = 0; j < 4; j++) acc[i][j] = f32x4{0.f, 0.f, 0.f, 0.f};
    size_t arow = ((size_t)o * ch + bm0 + am) * NH1;
    for (int st = 0; st < 8; st++) {
        int k0 = st * 32;
        float4 va4[4];
        #pragma unroll
        for (int i = 0; i < 4; i++)
            va4[i] = *(const float4*)&A[arow + k0 + kh * 16 + i * 4];
        float4 bv[4];
        const float4* wsl = (const float4*)(w2t + (size_t)st * 8192);
        #pragma unroll
        for (int i = 0; i < 4; i++) bv[i] = wsl[i * 256 + t];
        __syncthreads();
        {
            const float* va = (const float*)&va4[0];
            __bf16 h8[16], l8[16];
            #pragma unroll
            for (int j = 0; j < 16; j++) {
                __bf16 h = (__bf16)va[j];
                h8[j] = h;
                l8[j] = (__bf16)(va[j] - (float)h);
            }
            int kb0 = kh * 2;
            *(bf16x8*)&As2[0][kb0][am][0]     = *(bf16x8*)&h8[0];
            *(bf16x8*)&As2[0][kb0 + 1][am][0] = *(bf16x8*)&h8[8];
            *(bf16x8*)&As2[1][kb0][am][0]     = *(bf16x8*)&l8[0];
            *(bf16x8*)&As2[1][kb0 + 1][am][0] = *(bf16x8*)&l8[8];
            float4* bd = (float4*)&Bs2[0];
            #pragma unroll
            for (int i = 0; i < 4; i++) bd[i * 256 + t] = bv[i];
        }
        __syncthreads();
        bf16x8 ah[4], al[4], bh[4], blo[4];
        #pragma unroll
        for (int mf = 0; mf < 4; mf++) {
            int m = wr * 64 + mf * 16 + lr;
            ah[mf] = *(const bf16x8*)&As2[0][lk][m][0];
            al[mf] = *(const bf16x8*)&As2[1][lk][m][0];
        }
        #pragma unroll
        for (int nf = 0; nf < 4; nf++) {
            int n = wc * 64 + nf * 16 + lr;
            bh[nf]  = *(const bf16x8*)&Bs2[(size_t)lk * 1024 + n * 8];
            blo[nf] = *(const bf16x8*)&Bs2[4096 + (size_t)lk * 1024 + n * 8];
        }
        #pragma unroll
        for (int mf = 0; mf < 4; mf++)
            #pragma unroll
            for (int nf = 0; nf < 4; nf++) {
                acc[mf][nf] = __builtin_amdgcn_mfma_f32_16x16x32_bf16(ah[mf], bh[nf],  acc[mf][nf], 0, 0, 0);
                acc[mf][nf] = __builtin_amdgcn_mfma_f32_16x16x32_bf16(ah[mf], blo[nf], acc[mf][nf], 0, 0, 0);
                acc[mf][nf] = __builtin_amdgcn_mfma_f32_16x16x32_bf16(al[mf], bh[nf],  acc[mf][nf], 0, 0, 0);
            }
    }
    #pragma unroll
    for (int nf = 0; nf < 4; nf++) {
        int col = wc * 64 + nf * 16 + lr;       // NH2 = 128, single n-block
        float bias = b2[col];
        #pragma unroll
        for (int mf = 0; mf < 4; mf++)
            #pragma unroll
            for (int r = 0; r < 4; r++) {
                int rloc = wr * 64 + mf * 16 + lk * 4 + r;
                float v = acc[mf][nf][r] + bias;
                H2c[((size_t)o * ch + bm0 + rloc) * NH2 + col] = fmaxf(v, 0.f);
            }
    }
}

// ---------------- fp32 SGEMM (kept for GEMM3, N=33) ----------------------
template <int BM, int BN, int KTOT, int NACT, bool RELU>
__global__ __launch_bounds__(TPB)
void k_gemm(const float* __restrict__ A, const float* __restrict__ Bw,
            const float* __restrict__ bias, float* __restrict__ C, int chM) {
    constexpr int RT = BM / 16;
    constexpr int CT = BN / 16;
    const float* Az = A + (size_t)blockIdx.z * chM * KTOT;
    float*       Cz = C + (size_t)blockIdx.z * chM * NACT;
    __shared__ float As[8][BM];
    __shared__ float Bs[8][BN];
    int t = threadIdx.x;
    int bm0 = blockIdx.x * BM, bn0 = blockIdx.y * BN;
    int w = t >> 6, l = t & 63;
    int wr = w >> 1, wc = w & 1;
    int tm8 = l >> 3, tn8 = l & 7;
    int fa = wr * (BM / 2) + tm8 * RT;
    int fb = wc * (BN / 2) + tn8 * CT;
    int am, ak;
    if constexpr (BM == 128) { am = t & 127; ak = (t >> 7) * 4; }
    else                     { am = t & 63;  ak = (t >> 6) * 2; }
    constexpr int BNUM = BN / 32;
    int bk = t >> 5, bn = (t & 31) * BNUM;
    float acc[RT][CT] = {};
    for (int k0 = 0; k0 < KTOT; k0 += 8) {
        float avr[4];
        if constexpr (BM == 128) {
            float4 a4 = *reinterpret_cast<const float4*>(
                &Az[(size_t)(bm0 + am) * KTOT + k0 + ak]);
            avr[0] = a4.x; avr[1] = a4.y; avr[2] = a4.z; avr[3] = a4.w;
        } else {
            float2 a2 = *reinterpret_cast<const float2*>(
                &Az[(size_t)(bm0 + am) * KTOT + k0 + ak]);
            avr[0] = a2.x; avr[1] = a2.y;
        }
        float bvr[BNUM];
        #pragma unroll
        for (int j = 0; j < BNUM; j++) {
            int col = bn0 + bn + j;
            bvr[j] = (col < NACT) ? Bw[(size_t)(k0 + bk) * NACT + col] : 0.f;
        }
        __syncthreads();
        if constexpr (BM == 128) {
            As[ak + 0][am] = avr[0]; As[ak + 1][am] = avr[1];
            As[ak + 2][am] = avr[2]; As[ak + 3][am] = avr[3];
        } else {
            As[ak + 0][am] = avr[0]; As[ak + 1][am] = avr[1];
        }
        #pragma unroll
        for (int j = 0; j < BNUM; j++) Bs[bk][bn + j] = bvr[j];
        __syncthreads();
        #pragma unroll
        for (int kk = 0; kk < 8; kk++) {
            float ar[RT], br[CT];
            #pragma unroll
            for (int i = 0; i < RT; i += 4) {
                float4 a4 = *reinterpret_cast<const float4*>(&As[kk][fa + i]);
                ar[i] = a4.x; ar[i + 1] = a4.y; ar[i + 2] = a4.z; ar[i + 3] = a4.w;
            }
            #pragma unroll
            for (int i = 0; i < CT; i += 4) {
                float4 b4 = *reinterpret_cast<const float4*>(&Bs[kk][fb + i]);
                br[i] = b4.x; br[i + 1] = b4.y; br[i + 2] = b4.z; br[i + 3] = b4.w;
            }
            #pragma unroll
            for (int r = 0; r < RT; r++)
                #pragma unroll
                for (int cc = 0; cc < CT; cc++)
                    acc[r][cc] = fmaf(ar[r], br[cc], acc[r][cc]);
        }
    }
    float bb[CT];
    #pragma unroll
    for (int cc = 0; cc < CT; cc++) {
        int col = bn0 + fb + cc;
        bb[cc] = (col < NACT) ? bias[col] : 0.f;
    }
    #pragma unroll
    for (int r = 0; r < RT; r++) {
        size_t row = bm0 + fa + r;
        #pragma unroll
        for (int cc = 0; cc < CT; cc++) {
            int col = bn0 + fb + cc;
            if (col < NACT) {
                float v = acc[r][cc] + bb[cc];
                if (RELU) v = fmaxf(v, 0.f);
                Cz[row * NACT + col] = v;
            }
        }
    }
}

// ---------------- softmax over 4 offsets + weighted sum (per chunk) ------
__global__ __launch_bounds__(TPB)
void k_combine(const float* __restrict__ predsC, int row0, int ch,
               float* __restrict__ res) {
    int rl_ = blockIdx.x * TPB + threadIdx.x;
    if (rl_ >= ch) return;
    float p3[4];
    #pragma unroll
    for (int o = 0; o < 4; o++)
        p3[o] = predsC[((size_t)o * ch + rl_) * NOUT + 32];
    float mx = fmaxf(fmaxf(p3[0], p3[1]), fmaxf(p3[2], p3[3]));
    float e[4], sum = 0.f;
    #pragma unroll
    for (int o = 0; o < 4; o++) { e[o] = expf(p3[o] - mx); sum += e[o]; }
    float inv = 1.f / sum;
    int row = row0 + rl_;
    int b = row >> 14, pix = row & 16383;
    float* outb = res + (size_t)b * 32 * NPIX + pix;
    for (int c = 0; c < 32; c++) {
        float acc = 0.f;
        #pragma unroll
        for (int o = 0; o < 4; o++)
            acc = fmaf(predsC[((size_t)o * ch + rl_) * NOUT + c], e[o] * inv, acc);
        outb[(size_t)c * NPIX] = acc;
    }
}

// =========================================================================
static size_t align256(size_t x) { return (x + 255) & ~(size_t)255; }

static size_t plan_bytes(int ch) {
    size_t region = align256((size_t)ch * 4 * NH1 * 4)
                  + align256((size_t)ch * 4 * NH2 * 4)
                  + align256((size_t)ch * 4 * NOUT * 4);
    if (region < 33554432) region = 33554432;
    size_t t = align256(region);
    t += align256((size_t)Bn * FD * FH * FW * 4) * 2;   // featM, featP
    t += align256((size_t)Bn * GD * GH * GW * 4) * 2;   // guideM, guideP
    t += align256((size_t)Bn * 32 * NPIX * 4);          // phares (magres = d_out)
    t += align256((size_t)131072 * 2) * 2;              // w1t a/p
    t += align256((size_t)65536 * 2) * 2;               // w2t a/p
    t += align256((size_t)256 * 8) * 2;                 // relw a/p
    t += align256((size_t)NPIX * 4 * 4);                // idxb
    t += align256((size_t)NPIX * 4 * 8);                // relb
    return t;
}

extern "C" void kernel_launch(void* const* d_in, const int* in_sizes, int n_in,
                              void* d_out, int out_size, void* d_ws, size_t ws_size,
                              hipStream_t stream) {
    const float* feat  = (const float*)d_in[0];
    const float* coord = (const float*)d_in[1];
    const float* guide = (const float*)d_in[2];
    const float* aw1 = (const float*)d_in[3];
    const float* ab1 = (const float*)d_in[4];
    const float* aw2 = (const float*)d_in[5];
    const float* ab2 = (const float*)d_in[6];
    const float* aw3 = (const float*)d_in[7];
    const float* ab3 = (const float*)d_in[8];
    const float* pw1 = (const float*)d_in[9];
    const float* pb1 = (const float*)d_in[10];
    const float* pw2 = (const float*)d_in[11];
    const float* pb2 = (const float*)d_in[12];
    const float* pw3 = (const float*)d_in[13];
    const float* pb3 = (const float*)d_in[14];
    float* out = (float*)d_out;

    int ch = 0;
    const int cands[3] = {16384, 8192, 4096};
    for (int i = 0; i < 3; i++)
        if (plan_bytes(cands[i]) <= ws_size) { ch = cands[i]; break; }
    if (ch == 0) return;   // diagnostic: output stays poisoned, no fault
    const int nchk = (int)(ROWS / ch);

    char* ws = (char*)d_ws;
    size_t off = 0;
    auto alloc = [&](size_t bytes) -> void* {
        void* p = ws + off;
        off += align256(bytes);
        return p;
    };
    size_t region = align256((size_t)ch * 4 * NH1 * 4)
                  + align256((size_t)ch * 4 * NH2 * 4)
                  + align256((size_t)ch * 4 * NOUT * 4);
    if (region < 33554432) region = 33554432;
    char*   rbase  = (char*)alloc(region);
    float2* R0c    = (float2*)rbase;
    float*  H1c    = (float*)rbase;
    float*  H2c    = (float*)(rbase + align256((size_t)ch * 4 * NH1 * 4));
    float*  predsC = (float*)(rbase + align256((size_t)ch * 4 * NH1 * 4)
                                    + align256((size_t)ch * 4 * NH2 * 4));
    float*  featM  = (float*)alloc((size_t)Bn * FD * FH * FW * 4);
    float*  featP  = (float*)alloc((size_t)Bn * FD * FH * FW * 4);
    float*  guideM = (float*)alloc((size_t)Bn * GD * GH * GW * 4);
    float*  guideP = (float*)alloc((size_t)Bn * GD * GH * GW * 4);
    float*  phares = (float*)alloc((size_t)Bn * 32 * NPIX * 4);
    float*  magres = out;   // alias: consumed by iFFT rows before out written
    __bf16* w1ta   = (__bf16*)alloc((size_t)131072 * 2);
    __bf16* w1tp   = (__bf16*)alloc((size_t)131072 * 2);
    __bf16* w2ta   = (__bf16*)alloc((size_t)65536 * 2);
    __bf16* w2tp   = (__bf16*)alloc((size_t)65536 * 2);
    float2* relwa  = (float2*)alloc((size_t)256 * 8);
    float2* relwp  = (float2*)alloc((size_t)256 * 8);
    int*    idxb   = (int*)alloc((size_t)NPIX * 4 * 4);
    float2* relb   = (float2*)alloc((size_t)NPIX * 4 * 8);

    // ---- prep
    k_prep_w1<<<(256 * 256 + TPB - 1) / TPB, TPB, 0, stream>>>(aw1, w1ta, relwa);
    k_prep_w1<<<(256 * 256 + TPB - 1) / TPB, TPB, 0, stream>>>(pw1, w1tp, relwp);
    k_prep_w2<<<(256 * 128 + TPB - 1) / TPB, TPB, 0, stream>>>(aw2, w2ta);
    k_prep_w2<<<(256 * 128 + TPB - 1) / TPB, TPB, 0, stream>>>(pw2, w2tp);
    k_meta<<<(NPIX * 4 + TPB - 1) / TPB, TPB, 0, stream>>>(coord, idxb, relb);

    // ---- forward FFT: feat (1024 imgs 64x64)
    k_dft_rows_real<64><<<(Bn * FD * FH) / 4, TPB, 0, stream>>>(feat, R0c);
    k_dft_cols_magpha<64, 64><<<dim3(Bn * FD, FW / 32), TPB, 0, stream>>>(R0c, featM, featP);
    // ---- forward FFT: guide (1024 imgs 128x128) — 4 chunks of 256 imgs
    for (int g = 0; g < 4; g++) {
        const float* gin = guide + (size_t)g * 256 * NPIX;
        k_dft_rows_real<128><<<(256 * GH) / 2, TPB, 0, stream>>>(gin, R0c);
        k_dft_cols_magpha<128, 128><<<dim3(256, GW / 32), TPB, 0, stream>>>(
            R0c, guideM + (size_t)g * 256 * NPIX, guideP + (size_t)g * 256 * NPIX);
    }

    // ---- two MLP branches (mag with a_*, pha with p_*), row-chunked
    for (int br = 0; br < 2; br++) {
        const float*  fX   = br ? featP  : featM;
        const float*  gX   = br ? guideP : guideM;
        const __bf16* w1t  = br ? w1tp : w1ta;
        const float2* relw = br ? relwp : relwa;
        const float*  b1   = br ? pb1 : ab1;
        const __bf16* w2t  = br ? w2tp : w2ta;
        const float*  b2   = br ? pb2 : ab2;
        const float*  w3   = br ? pw3 : aw3;
        const float*  b3   = br ? pb3 : ab3;
        float* resb = br ? phares : magres;
        for (int c = 0; c < nchk; c++) {
            int row0 = c * ch;
            k_gemm1_mfma<<<dim3(ch / 128, 2, 4), TPB, 0, stream>>>(
                fX, gX, idxb, relb, row0, ch, w1t, relw, b1, H1c);
            k_gemm2_mfma<<<dim3(ch / 128, 1, 4), TPB, 0, stream>>>(
                H1c, w2t, b2, H2c, ch);
            k_gemm<64, 64, 128, 33, false><<<dim3(ch / 64, 1, 4), TPB, 0, stream>>>(
                H2c, w3, b3, predsC, ch);
            k_combine<<<ch / TPB, TPB, 0, stream>>>(predsC, row0, ch, resb);
        }
    }

    // ---- inverse FFT (256 imgs 128x128) + abs
    k_idft_rows_mp<<<(Bn * 32 * GH) / 2, TPB, 0, stream>>>(magres, phares, R0c);
    k_idft_cols_abs<<<dim3(Bn * 32, GW / 32), TPB, 0, stream>>>(R0c, out);
}

// Round 6
// 3114.036 us; speedup vs baseline: 1.8236x; 1.2785x over previous
//
#include <hip/hip_runtime.h>
#include <cmath>

#define TPB 256

static constexpr int   Bn   = 8;
static constexpr int   FD   = 128, GD = 128;
static constexpr int   FH   = 64,  FW = 64;
static constexpr int   GH   = 128, GW = 128;
static constexpr int   NPIX = GH * GW;          // 16384
static constexpr long  ROWS = (long)Bn * NPIX;  // 131072
static constexpr int   NH1  = 256, NH2 = 128, NOUT = 33;
static constexpr float TWO_PI = 6.28318530717958647692f;

typedef __attribute__((ext_vector_type(8))) __bf16 bf16x8;
typedef __attribute__((ext_vector_type(4))) float  f32x4;

// ---------------- gather metadata per (pixel, offset) -------------------
__global__ __launch_bounds__(TPB)
void k_meta(const float* __restrict__ coord, int* __restrict__ idxb,
            float2* __restrict__ relb) {
    int t = blockIdx.x * TPB + threadIdx.x;
    if (t >= NPIX * 4) return;
    int pix = t >> 2, o = t & 3;
    float cy = coord[pix * 2 + 0], cx = coord[pix * 2 + 1];
    float vx = (o < 2) ? -1.f : 1.f;       // ref loop order: vx outer, vy inner
    float vy = (o & 1) ? 1.f : -1.f;
    float cyo = cy + vx / 64.f, cxo = cx + vy / 64.f;
    float fy = rintf(((cyo + 1.f) * 64.f - 1.f) * 0.5f);
    float fx = rintf(((cxo + 1.f) * 64.f - 1.f) * 0.5f);
    bool valid = (fy >= 0.f) && (fy < 64.f) && (fx >= 0.f) && (fx < 64.f);
    int iy = min(max((int)fy, 0), 63), ix = min(max((int)fx, 0), 63);
    float qcy = valid ? (-1.f + (2.f * iy + 1.f) / 64.f) : 0.f;
    float qcx = valid ? (-1.f + (2.f * ix + 1.f) / 64.f) : 0.f;
    relb[t] = make_float2((cy - qcy) * 64.f, (cx - qcx) * 64.f);
    idxb[t] = valid ? (iy * 64 + ix) : -1;
}

// ---------------- weight prep: split-bf16 + MFMA-layout transpose --------
__global__ __launch_bounds__(TPB)
void k_prep_w1(const float* __restrict__ w1, __bf16* __restrict__ w1t,
               float2* __restrict__ relw) {
    int i = blockIdx.x * TPB + threadIdx.x;
    if (i < 256) relw[i] = make_float2(w1[256 * 256 + i], w1[257 * 256 + i]);
    if (i >= 256 * 256) return;
    int k = i >> 8, n = i & 255;
    float v = w1[k * 256 + n];
    __bf16 h = (__bf16)v;
    __bf16 lo = (__bf16)(v - (float)h);
    int nb = n >> 7, nl = n & 127, st = k >> 5, kb = (k >> 3) & 3, j = k & 7;
    size_t slab = ((size_t)nb * 8 + st) * 8192;
    w1t[slab + 0    + kb * 1024 + nl * 8 + j] = h;
    w1t[slab + 4096 + kb * 1024 + nl * 8 + j] = lo;
}

__global__ __launch_bounds__(TPB)
void k_prep_w2(const float* __restrict__ w2, __bf16* __restrict__ w2t) {
    int i = blockIdx.x * TPB + threadIdx.x;
    if (i >= 256 * 128) return;
    int k = i >> 7, n = i & 127;
    float v = w2[k * 128 + n];
    __bf16 h = (__bf16)v;
    __bf16 lo = (__bf16)(v - (float)h);
    int st = k >> 5, kb = (k >> 3) & 3, j = k & 7;
    size_t slab = (size_t)st * 8192;
    w2t[slab + 0    + kb * 1024 + n * 8 + j] = h;
    w2t[slab + 4096 + kb * 1024 + n * 8 + j] = lo;
}

// ---------------- DFT constant-matrix prep (split-bf16, slab layouts) ----
// mode 0: fwd pass1 B  [k=x][re(v)|im(v)]      (B-type), P = W (64/128)
// mode 1: fwd pass2 A  [m=2u+p][k'=pl*P+y]     (A-type), P = H
// mode 2: inv pass1 B  [k=2v+q][re(x)|im(x)]   (B-type), 256x256
// mode 3: inv pass2 A  [m=2y+p][k'=pl*128+u]   (A-type), 256x256
// A-type layout: [mb][st][hl][kb][ml128][j8];  B-type: [nb][st][hl][kb][nl128][j8]
__global__ __launch_bounds__(TPB)
void k_prep_fftmat(int mode, int P, __bf16* __restrict__ outm) {
    int R, C, ST;
    bool Atype;
    if (mode == 0)      { R = P;   C = 2*P; ST = P >> 5; Atype = false; }
    else if (mode == 1) { R = 2*P; C = 2*P; ST = P >> 4; Atype = true;  }
    else                { R = 256; C = 256; ST = 8;      Atype = (mode == 3); }
    int i = blockIdx.x * TPB + threadIdx.x;
    if (i >= R * C) return;
    int r = i / C, c = i % C;
    float s, co, val;
    if (mode == 0) {
        int pl = (c >= P) ? 1 : 0, v = c - pl * P;
        int kv = (r * v) % P;
        sincosf(TWO_PI * (float)kv / (float)P, &s, &co);
        val = pl ? -s : co;                       // e^{-2pi i xv/W}
    } else if (mode == 1) {
        int u = r >> 1, p = r & 1;
        int pl = (c >= P) ? 1 : 0, y = c - pl * P;
        int uy = (u * y) % P;
        sincosf(TWO_PI * (float)uy / (float)P, &s, &co);
        val = (p == 0) ? (pl ? s : co) : (pl ? co : -s);
    } else if (mode == 2) {
        int v = r >> 1, q = r & 1;
        int pl = c >> 7, x = c & 127;
        int vx = (v * x) & 127;
        sincosf(TWO_PI * (float)vx / 128.f, &s, &co);
        val = (q == 0) ? (pl ? s : co) : (pl ? co : -s);
    } else {
        int y = r >> 1, p = r & 1;
        int pl = c >> 7, u = c & 127;
        int uy = (u * y) & 127;
        sincosf(TWO_PI * (float)uy / 128.f, &s, &co);
        val = (p == 0) ? (pl ? -s : co) : (pl ? co : s);
    }
    int blk, lin, kidx;
    if (Atype) { blk = r >> 7; lin = r & 127; kidx = c; }
    else       { blk = c >> 7; lin = c & 127; kidx = r; }
    int st = kidx >> 5, kb = (kidx >> 3) & 3, j = kidx & 7;
    __bf16 h = (__bf16)val;
    __bf16 lo = (__bf16)(val - (float)h);
    size_t base = (((size_t)blk * ST + st) * 2) * 4096 + (size_t)kb * 1024 + lin * 8 + j;
    outm[base] = h;
    outm[base + 4096] = lo;
}

// ---------------- FFT pass 1: data(fp32) x const -> Y slabs (bf16 h/l) ---
// C[m][c] = sum_k A[m][k] * Bc[k][c]; epilogue scatters into pass-2 B-slab
// layout per image: [st2][hl][kb][v SW][j], plane = c/SW, k' = plane*H + y.
template <int KTOT, int SW, int HROWS>
__global__ __launch_bounds__(TPB)
void k_fft_p1(const float* __restrict__ A, const __bf16* __restrict__ Bc,
              __bf16* __restrict__ Yslab) {
    constexpr int ST     = KTOT / 32;
    constexpr int LOG2H  = (HROWS == 64) ? 6 : 7;
    constexpr int CHUNK  = 64 * SW;               // bf16 per (img, st2)
    constexpr int ST2T   = HROWS / 16;            // pass-2 k-steps
    constexpr int IMGSLB = ST2T * CHUNK;
    __shared__ __align__(16) __bf16 As2[2][4][128][8];
    __shared__ __align__(16) __bf16 Bs2[8192];
    int t = threadIdx.x;
    int bm0 = blockIdx.x * 128;
    int nb  = blockIdx.y;
    int w = t >> 6, l = t & 63;
    int wr = w >> 1, wc = w & 1;
    int lr = l & 15, lk = l >> 4;
    int am = t >> 1, kh = t & 1;
    f32x4 acc[4][4];
    #pragma unroll
    for (int i = 0; i < 4; i++)
        #pragma unroll
        for (int j = 0; j < 4; j++) acc[i][j] = f32x4{0.f, 0.f, 0.f, 0.f};
    for (int st = 0; st < ST; st++) {
        const float* arow = A + (size_t)(bm0 + am) * KTOT + st * 32 + kh * 16;
        float4 va4[4];
        #pragma unroll
        for (int i = 0; i < 4; i++) va4[i] = ((const float4*)arow)[i];
        const float4* wsl = (const float4*)(Bc + ((size_t)nb * ST + st) * 8192);
        float4 bv[4];
        #pragma unroll
        for (int i = 0; i < 4; i++) bv[i] = wsl[i * 256 + t];
        __syncthreads();
        {
            const float* va = (const float*)&va4[0];
            __bf16 h8[16], l8[16];
            #pragma unroll
            for (int j = 0; j < 16; j++) {
                __bf16 h = (__bf16)va[j];
                h8[j] = h;
                l8[j] = (__bf16)(va[j] - (float)h);
            }
            int kb0 = kh * 2;
            *(bf16x8*)&As2[0][kb0][am][0]     = *(bf16x8*)&h8[0];
            *(bf16x8*)&As2[0][kb0 + 1][am][0] = *(bf16x8*)&h8[8];
            *(bf16x8*)&As2[1][kb0][am][0]     = *(bf16x8*)&l8[0];
            *(bf16x8*)&As2[1][kb0 + 1][am][0] = *(bf16x8*)&l8[8];
            float4* bd = (float4*)&Bs2[0];
            #pragma unroll
            for (int i = 0; i < 4; i++) bd[i * 256 + t] = bv[i];
        }
        __syncthreads();
        bf16x8 ah[4], al[4], bh[4], blo[4];
        #pragma unroll
        for (int mf = 0; mf < 4; mf++) {
            int m = wr * 64 + mf * 16 + lr;
            ah[mf] = *(const bf16x8*)&As2[0][lk][m][0];
            al[mf] = *(const bf16x8*)&As2[1][lk][m][0];
        }
        #pragma unroll
        for (int nf = 0; nf < 4; nf++) {
            int n = wc * 64 + nf * 16 + lr;
            bh[nf]  = *(const bf16x8*)&Bs2[(size_t)lk * 1024 + n * 8];
            blo[nf] = *(const bf16x8*)&Bs2[4096 + (size_t)lk * 1024 + n * 8];
        }
        #pragma unroll
        for (int mf = 0; mf < 4; mf++)
            #pragma unroll
            for (int nf = 0; nf < 4; nf++) {
                acc[mf][nf] = __builtin_amdgcn_mfma_f32_16x16x32_bf16(ah[mf], bh[nf],  acc[mf][nf], 0, 0, 0);
                acc[mf][nf] = __builtin_amdgcn_mfma_f32_16x16x32_bf16(ah[mf], blo[nf], acc[mf][nf], 0, 0, 0);
                acc[mf][nf] = __builtin_amdgcn_mfma_f32_16x16x32_bf16(al[mf], bh[nf],  acc[mf][nf], 0, 0, 0);
            }
    }
    // epilogue: scatter into pass-2 B-slab layout (hi/lo bf16)
    #pragma unroll
    for (int nf = 0; nf < 4; nf++) {
        int Cg = nb * 128 + wc * 64 + nf * 16 + lr;
        int plane = Cg / SW;
        int v = Cg % SW;
        #pragma unroll
        for (int mf = 0; mf < 4; mf++)
            #pragma unroll
            for (int r = 0; r < 4; r++) {
                int rloc = wr * 64 + mf * 16 + lk * 4 + r;
                int grow = bm0 + rloc;
                int img = grow >> LOG2H;
                int y = grow & (HROWS - 1);
                int kp = plane * HROWS + y;
                int st2 = kp >> 5, kb2 = (kp >> 3) & 3, j2 = kp & 7;
                size_t a = (size_t)img * IMGSLB + (size_t)st2 * CHUNK
                         + (size_t)kb2 * (SW * 8) + v * 8 + j2;
                float val = acc[mf][nf][r];
                __bf16 h = (__bf16)val;
                Yslab[a] = h;
                Yslab[a + 32 * SW] = (__bf16)(val - (float)h);
            }
    }
}

// ---------------- FFT pass 2: const(A) x Y slabs -> mag/pha or abs -------
// EPI 0: guide mag/pha (img per block, mb in {0,1})
// EPI 1: feat mag/pha (2 imgs per block in N; mb = 0)
// EPI 2: inverse abs * 1/16384 -> out
template <int HROWS, int SW, int EPI>
__global__ __launch_bounds__(TPB)
void k_fft_p2(const __bf16* __restrict__ Ac, const __bf16* __restrict__ Yslab,
              float* __restrict__ out0, float* __restrict__ out1) {
    constexpr int ST2    = HROWS / 16;
    constexpr int CHUNK  = 64 * SW;
    constexpr int IMGSLB = ST2 * CHUNK;
    __shared__ __align__(16) __bf16 As2[2][4][128][8];
    __shared__ __align__(16) __bf16 Bs2[8192];
    int t = threadIdx.x;
    int imgx = blockIdx.x;
    int mb   = blockIdx.y;
    int w = t >> 6, l = t & 63;
    int wr = w >> 1, wc = w & 1;
    int lr = l & 15, lk = l >> 4;
    f32x4 acc[4][4];
    #pragma unroll
    for (int i = 0; i < 4; i++)
        #pragma unroll
        for (int j = 0; j < 4; j++) acc[i][j] = f32x4{0.f, 0.f, 0.f, 0.f};
    for (int st = 0; st < ST2; st++) {
        const float4* asl = (const float4*)(Ac + ((size_t)mb * ST2 + st) * 8192);
        float4 av[4];
        #pragma unroll
        for (int i = 0; i < 4; i++) av[i] = asl[i * 256 + t];
        float4 bv[4];
        if constexpr (EPI == 1) {
            int u_ = t & 127, isel = t >> 7;
            const float4* bsl = (const float4*)(Yslab
                + (size_t)(imgx * 2 + isel) * IMGSLB + (size_t)st * CHUNK);
            #pragma unroll
            for (int i = 0; i < 4; i++) bv[i] = bsl[i * 128 + u_];
        } else {
            const float4* bsl = (const float4*)(Yslab
                + (size_t)imgx * IMGSLB + (size_t)st * CHUNK);
            #pragma unroll
            for (int i = 0; i < 4; i++) bv[i] = bsl[i * 256 + t];
        }
        __syncthreads();
        {
            float4* ad = (float4*)&As2[0][0][0][0];
            #pragma unroll
            for (int i = 0; i < 4; i++) ad[i * 256 + t] = av[i];
            float4* bd = (float4*)&Bs2[0];
            if constexpr (EPI == 1) {
                int u_ = t & 127, isel = t >> 7;
                #pragma unroll
                for (int i = 0; i < 4; i++) {
                    int f = i * 128 + u_;
                    int hlkb = f >> 6, v = f & 63;
                    bd[hlkb * 128 + isel * 64 + v] = bv[i];
                }
            } else {
                #pragma unroll
                for (int i = 0; i < 4; i++) bd[i * 256 + t] = bv[i];
            }
        }
        __syncthreads();
        bf16x8 ah[4], al[4], bh[4], blo[4];
        #pragma unroll
        for (int mf = 0; mf < 4; mf++) {
            int m = wr * 64 + mf * 16 + lr;
            ah[mf] = *(const bf16x8*)&As2[0][lk][m][0];
            al[mf] = *(const bf16x8*)&As2[1][lk][m][0];
        }
        #pragma unroll
        for (int nf = 0; nf < 4; nf++) {
            int n = wc * 64 + nf * 16 + lr;
            bh[nf]  = *(const bf16x8*)&Bs2[(size_t)lk * 1024 + n * 8];
            blo[nf] = *(const bf16x8*)&Bs2[4096 + (size_t)lk * 1024 + n * 8];
        }
        #pragma unroll
        for (int mf = 0; mf < 4; mf++)
            #pragma unroll
            for (int nf = 0; nf < 4; nf++) {
                acc[mf][nf] = __builtin_amdgcn_mfma_f32_16x16x32_bf16(ah[mf], bh[nf],  acc[mf][nf], 0, 0, 0);
                acc[mf][nf] = __builtin_amdgcn_mfma_f32_16x16x32_bf16(ah[mf], blo[nf], acc[mf][nf], 0, 0, 0);
                acc[mf][nf] = __builtin_amdgcn_mfma_f32_16x16x32_bf16(al[mf], bh[nf],  acc[mf][nf], 0, 0, 0);
            }
    }
    // epilogue: rows are (re,im)-interleaved pairs
    #pragma unroll
    for (int nf = 0; nf < 4; nf++) {
        int v = wc * 64 + nf * 16 + lr;
        #pragma unroll
        for (int mf = 0; mf < 4; mf++) {
            int mlocb = wr * 64 + mf * 16 + lk * 4;
            #pragma unroll
            for (int rp = 0; rp < 4; rp += 2) {
                float re = acc[mf][nf][rp], im = acc[mf][nf][rp + 1];
                int m = mb * 128 + mlocb + rp;
                int u = m >> 1;
                if constexpr (EPI == 0) {
                    size_t oi = (size_t)imgx * (HROWS * SW) + (size_t)u * SW + v;
                    out0[oi] = sqrtf(re * re + im * im);
                    out1[oi] = atan2f(im, re);
                } else if constexpr (EPI == 1) {
                    int isel = v >> 6, vv = v & 63;
                    size_t oi = (size_t)(imgx * 2 + isel) * 4096 + (size_t)u * 64 + vv;
                    out0[oi] = sqrtf(re * re + im * im);
                    out1[oi] = atan2f(im, re);
                } else {
                    size_t oi = (size_t)imgx * 16384 + (size_t)u * 128 + v;
                    out0[oi] = sqrtf(re * re + im * im) * (1.f / 16384.f);
                }
            }
        }
    }
}

// ---------------- mag/pha -> interleaved complex (iFFT pass-1 input) -----
__global__ __launch_bounds__(TPB)
void k_prep_zc(const float* __restrict__ mag, const float* __restrict__ pha,
               float* __restrict__ Zc) {
    int i = blockIdx.x * TPB + threadIdx.x;   // over 256*128*128
    float m = mag[i], p = pha[i];
    float s, c; sincosf(p, &s, &c);
    Zc[2 * i]     = m * c;
    Zc[2 * i + 1] = m * s;
}

// ---------------- GEMM1: gather + split-bf16 MFMA ------------------------
__global__ __launch_bounds__(TPB)
void k_gemm1_mfma(const float* __restrict__ featX, const float* __restrict__ guideX,
                  const int* __restrict__ idxb, const float2* __restrict__ relb,
                  int row0, int ch, const __bf16* __restrict__ w1t,
                  const float2* __restrict__ relw, const float* __restrict__ b1,
                  float* __restrict__ H1c) {
    __shared__ __align__(16) __bf16 As2[2][4][128][8];
    __shared__ __align__(16) __bf16 Bs2[8192];
    __shared__ int    sfo[128];
    __shared__ int    sgo[128];
    __shared__ float2 srel[128];
    int t = threadIdx.x;
    int o = blockIdx.z;
    int bm0 = blockIdx.x * 128;
    int nb  = blockIdx.y;
    int bn0 = nb * 128;
    if (t < 128) {
        int row = row0 + bm0 + t;
        int b = row >> 14, pix = row & 16383;
        int id = idxb[pix * 4 + o];
        sfo[t] = (id >= 0) ? (b * (FD * FH * FW) + id) : -1;
        sgo[t] = b * (GD * GH * GW) + pix;
        srel[t] = relb[pix * 4 + o];
    }
    int w = t >> 6, l = t & 63;
    int wr = w >> 1, wc = w & 1;
    int lr = l & 15, lk = l >> 4;
    int am = t >> 1, kh = t & 1;
    const __bf16* wbase = w1t + (size_t)nb * 65536;
    f32x4 acc[4][4];
    #pragma unroll
    for (int i = 0; i < 4; i++)
        #pragma unroll
        for (int j = 0; j < 4; j++) acc[i][j] = f32x4{0.f, 0.f, 0.f, 0.f};
    __syncthreads();   // sfo/sgo/srel ready
    for (int st = 0; st < 8; st++) {
        int k0 = st * 32;
        float va[16];
        if (st < 4) {
            int fo = sfo[am];
            int kbase = k0 + kh * 16;
            if (fo >= 0) {
                #pragma unroll
                for (int j = 0; j < 16; j++)
                    va[j] = featX[(size_t)fo + (size_t)(kbase + j) * (FH * FW)];
            } else {
                #pragma unroll
                for (int j = 0; j < 16; j++) va[j] = 0.f;
            }
        } else {
            int go = sgo[am];
            int kbase = k0 - 128 + kh * 16;
            #pragma unroll
            for (int j = 0; j < 16; j++)
                va[j] = guideX[(size_t)go + (size_t)(kbase + j) * (GH * GW)];
        }
        float4 bv[4];
        const float4* wsl = (const float4*)(wbase + (size_t)st * 8192);
        #pragma unroll
        for (int i = 0; i < 4; i++) bv[i] = wsl[i * 256 + t];
        __syncthreads();
        {
            __bf16 h8[16], l8[16];
            #pragma unroll
            for (int j = 0; j < 16; j++) {
                __bf16 h = (__bf16)va[j];
                h8[j] = h;
                l8[j] = (__bf16)(va[j] - (float)h);
            }
            int kb0 = kh * 2;
            *(bf16x8*)&As2[0][kb0][am][0]     = *(bf16x8*)&h8[0];
            *(bf16x8*)&As2[0][kb0 + 1][am][0] = *(bf16x8*)&h8[8];
            *(bf16x8*)&As2[1][kb0][am][0]     = *(bf16x8*)&l8[0];
            *(bf16x8*)&As2[1][kb0 + 1][am][0] = *(bf16x8*)&l8[8];
            float4* bd = (float4*)&Bs2[0];
            #pragma unroll
            for (int i = 0; i < 4; i++) bd[i * 256 + t] = bv[i];
        }
        __syncthreads();
        bf16x8 ah[4], al[4], bh[4], blo[4];
        #pragma unroll
        for (int mf = 0; mf < 4; mf++) {
            int m = wr * 64 + mf * 16 + lr;
            ah[mf] = *(const bf16x8*)&As2[0][lk][m][0];
            al[mf] = *(const bf16x8*)&As2[1][lk][m][0];
        }
        #pragma unroll
        for (int nf = 0; nf < 4; nf++) {
            int n = wc * 64 + nf * 16 + lr;
            bh[nf]  = *(const bf16x8*)&Bs2[(size_t)lk * 1024 + n * 8];
            blo[nf] = *(const bf16x8*)&Bs2[4096 + (size_t)lk * 1024 + n * 8];
        }
        #pragma unroll
        for (int mf = 0; mf < 4; mf++)
            #pragma unroll
            for (int nf = 0; nf < 4; nf++) {
                acc[mf][nf] = __builtin_amdgcn_mfma_f32_16x16x32_bf16(ah[mf], bh[nf],  acc[mf][nf], 0, 0, 0);
                acc[mf][nf] = __builtin_amdgcn_mfma_f32_16x16x32_bf16(ah[mf], blo[nf], acc[mf][nf], 0, 0, 0);
                acc[mf][nf] = __builtin_amdgcn_mfma_f32_16x16x32_bf16(al[mf], bh[nf],  acc[mf][nf], 0, 0, 0);
            }
    }
    #pragma unroll
    for (int nf = 0; nf < 4; nf++) {
        int col = bn0 + wc * 64 + nf * 16 + lr;
        float bias = b1[col];
        float2 rw = relw[col];
        #pragma unroll
        for (int mf = 0; mf < 4; mf++)
            #pragma unroll
            for (int r = 0; r < 4; r++) {
                int rloc = wr * 64 + mf * 16 + lk * 4 + r;
                float2 rr = srel[rloc];
                float v = acc[mf][nf][r] + bias + rr.x * rw.x + rr.y * rw.y;
                H1c[((size_t)o * ch + bm0 + rloc) * NH1 + col] = fmaxf(v, 0.f);
            }
    }
}

// ---------------- GEMM2: H1 (fp32) x W2, split-bf16 MFMA -----------------
__global__ __launch_bounds__(TPB)
void k_gemm2_mfma(const float* __restrict__ A, const __bf16* __restrict__ w2t,
                  const float* __restrict__ b2, float* __restrict__ H2c, int ch) {
    __shared__ __align__(16) __bf16 As2[2][4][128][8];
    __shared__ __align__(16) __bf16 Bs2[8192];
    int t = threadIdx.x;
    int o = blockIdx.z;
    int bm0 = blockIdx.x * 128;
    int w = t >> 6, l = t & 63;
    int wr = w >> 1, wc = w & 1;
    int lr = l & 15, lk = l >> 4;
    int am = t >> 1, kh = t & 1;
    f32x4 acc[4][4];
    #pragma unroll
    for (int i = 0; i < 4; i++)
        #pragma unroll
        for (int j = 0; j < 4; j++) acc[i][j] = f32x4{0.f, 0.f, 0.f, 0.f};
    size_t arow = ((size_t)o * ch + bm0 + am) * NH1;
    for (int st = 0; st < 8; st++) {
        int k0 = st * 32;
        float4 va4[4];
        #pragma unroll
        for (int i = 0; i < 4; i++)
            va4[i] = *(const float4*)&A[arow + k0 + kh * 16 + i * 4];
        float4 bv[4];
        const float4* wsl = (const float4*)(w2t + (size_t)st * 8192);
        #pragma unroll
        for (int i = 0; i < 4; i++) bv[i] = wsl[i * 256 + t];
        __syncthreads();
        {
            const float* va = (const float*)&va4[0];
            __bf16 h8[16], l8[16];
            #pragma unroll
            for (int j = 0; j < 16; j++) {
                __bf16 h = (__bf16)va[j];
                h8[j] = h;
                l8[j] = (__bf16)(va[j] - (float)h);
            }
            int kb0 = kh * 2;
            *(bf16x8*)&As2[0][kb0][am][0]     = *(bf16x8*)&h8[0];
            *(bf16x8*)&As2[0][kb0 + 1][am][0] = *(bf16x8*)&h8[8];
            *(bf16x8*)&As2[1][kb0][am][0]     = *(bf16x8*)&l8[0];
            *(bf16x8*)&As2[1][kb0 + 1][am][0] = *(bf16x8*)&l8[8];
            float4* bd = (float4*)&Bs2[0];
            #pragma unroll
            for (int i = 0; i < 4; i++) bd[i * 256 + t] = bv[i];
        }
        __syncthreads();
        bf16x8 ah[4], al[4], bh[4], blo[4];
        #pragma unroll
        for (int mf = 0; mf < 4; mf++) {
            int m = wr * 64 + mf * 16 + lr;
            ah[mf] = *(const bf16x8*)&As2[0][lk][m][0];
            al[mf] = *(const bf16x8*)&As2[1][lk][m][0];
        }
        #pragma unroll
        for (int nf = 0; nf < 4; nf++) {
            int n = wc * 64 + nf * 16 + lr;
            bh[nf]  = *(const bf16x8*)&Bs2[(size_t)lk * 1024 + n * 8];
            blo[nf] = *(const bf16x8*)&Bs2[4096 + (size_t)lk * 1024 + n * 8];
        }
        #pragma unroll
        for (int mf = 0; mf < 4; mf++)
            #pragma unroll
            for (int nf = 0; nf < 4; nf++) {
                acc[mf][nf] = __builtin_amdgcn_mfma_f32_16x16x32_bf16(ah[mf], bh[nf],  acc[mf][nf], 0, 0, 0);
                acc[mf][nf] = __builtin_amdgcn_mfma_f32_16x16x32_bf16(ah[mf], blo[nf], acc[mf][nf], 0, 0, 0);
                acc[mf][nf] = __builtin_amdgcn_mfma_f32_16x16x32_bf16(al[mf], bh[nf],  acc[mf][nf], 0, 0, 0);
            }
    }
    #pragma unroll
    for (int nf = 0; nf < 4; nf++) {
        int col = wc * 64 + nf * 16 + lr;
        float bias = b2[col];
        #pragma unroll
        for (int mf = 0; mf < 4; mf++)
            #pragma unroll
            for (int r = 0; r < 4; r++) {
                int rloc = wr * 64 + mf * 16 + lk * 4 + r;
                float v = acc[mf][nf][r] + bias;
                H2c[((size_t)o * ch + bm0 + rloc) * NH2 + col] = fmaxf(v, 0.f);
            }
    }
}

// ---------------- fp32 SGEMM (GEMM3, N=33) -------------------------------
template <int BM, int BN, int KTOT, int NACT, bool RELU>
__global__ __launch_bounds__(TPB)
void k_gemm(const float* __restrict__ A, const float* __restrict__ Bw,
            const float* __restrict__ bias, float* __restrict__ C, int chM) {
    constexpr int RT = BM / 16;
    constexpr int CT = BN / 16;
    const float* Az = A + (size_t)blockIdx.z * chM * KTOT;
    float*       Cz = C + (size_t)blockIdx.z * chM * NACT;
    __shared__ float As[8][BM];
    __shared__ float Bs[8][BN];
    int t = threadIdx.x;
    int bm0 = blockIdx.x * BM, bn0 = blockIdx.y * BN;
    int w = t >> 6, l = t & 63;
    int wr = w >> 1, wc = w & 1;
    int tm8 = l >> 3, tn8 = l & 7;
    int fa = wr * (BM / 2) + tm8 * RT;
    int fb = wc * (BN / 2) + tn8 * CT;
    int am, ak;
    if constexpr (BM == 128) { am = t & 127; ak = (t >> 7) * 4; }
    else                     { am = t & 63;  ak = (t >> 6) * 2; }
    constexpr int BNUM = BN / 32;
    int bk = t >> 5, bn = (t & 31) * BNUM;
    float acc[RT][CT] = {};
    for (int k0 = 0; k0 < KTOT; k0 += 8) {
        float avr[4];
        if constexpr (BM == 128) {
            float4 a4 = *reinterpret_cast<const float4*>(
                &Az[(size_t)(bm0 + am) * KTOT + k0 + ak]);
            avr[0] = a4.x; avr[1] = a4.y; avr[2] = a4.z; avr[3] = a4.w;
        } else {
            float2 a2 = *reinterpret_cast<const float2*>(
                &Az[(size_t)(bm0 + am) * KTOT + k0 + ak]);
            avr[0] = a2.x; avr[1] = a2.y;
        }
        float bvr[BNUM];
        #pragma unroll
        for (int j = 0; j < BNUM; j++) {
            int col = bn0 + bn + j;
            bvr[j] = (col < NACT) ? Bw[(size_t)(k0 + bk) * NACT + col] : 0.f;
        }
        __syncthreads();
        if constexpr (BM == 128) {
            As[ak + 0][am] = avr[0]; As[ak + 1][am] = avr[1];
            As[ak + 2][am] = avr[2]; As[ak + 3][am] = avr[3];
        } else {
            As[ak + 0][am] = avr[0]; As[ak + 1][am] = avr[1];
        }
        #pragma unroll
        for (int j = 0; j < BNUM; j++) Bs[bk][bn + j] = bvr[j];
        __syncthreads();
        #pragma unroll
        for (int kk = 0; kk < 8; kk++) {
            float ar[RT], br[CT];
            #pragma unroll
            for (int i = 0; i < RT; i += 4) {
                float4 a4 = *reinterpret_cast<const float4*>(&As[kk][fa + i]);
                ar[i] = a4.x; ar[i + 1] = a4.y; ar[i + 2] = a4.z; ar[i + 3] = a4.w;
            }
            #pragma unroll
            for (int i = 0; i < CT; i += 4) {
                float4 b4 = *reinterpret_cast<const float4*>(&Bs[kk][fb + i]);
                br[i] = b4.x; br[i + 1] = b4.y; br[i + 2] = b4.z; br[i + 3] = b4.w;
            }
            #pragma unroll
            for (int r = 0; r < RT; r++)
                #pragma unroll
                for (int cc = 0; cc < CT; cc++)
                    acc[r][cc] = fmaf(ar[r], br[cc], acc[r][cc]);
        }
    }
    float bb[CT];
    #pragma unroll
    for (int cc = 0; cc < CT; cc++) {
        int col = bn0 + fb + cc;
        bb[cc] = (col < NACT) ? bias[col] : 0.f;
    }
    #pragma unroll
    for (int r = 0; r < RT; r++) {
        size_t row = bm0 + fa + r;
        #pragma unroll
        for (int cc = 0; cc < CT; cc++) {
            int col = bn0 + fb + cc;
            if (col < NACT) {
                float v = acc[r][cc] + bb[cc];
                if (RELU) v = fmaxf(v, 0.f);
                Cz[row * NACT + col] = v;
            }
        }
    }
}

// ---------------- softmax over 4 offsets + weighted sum (per chunk) ------
__global__ __launch_bounds__(TPB)
void k_combine(const float* __restrict__ predsC, int row0, int ch,
               float* __restrict__ res) {
    int rl_ = blockIdx.x * TPB + threadIdx.x;
    if (rl_ >= ch) return;
    float p3[4];
    #pragma unroll
    for (int o = 0; o < 4; o++)
        p3[o] = predsC[((size_t)o * ch + rl_) * NOUT + 32];
    float mx = fmaxf(fmaxf(p3[0], p3[1]), fmaxf(p3[2], p3[3]));
    float e[4], sum = 0.f;
    #pragma unroll
    for (int o = 0; o < 4; o++) { e[o] = expf(p3[o] - mx); sum += e[o]; }
    float inv = 1.f / sum;
    int row = row0 + rl_;
    int b = row >> 14, pix = row & 16383;
    float* outb = res + (size_t)b * 32 * NPIX + pix;
    for (int c = 0; c < 32; c++) {
        float acc = 0.f;
        #pragma unroll
        for (int o = 0; o < 4; o++)
            acc = fmaf(predsC[((size_t)o * ch + rl_) * NOUT + c], e[o] * inv, acc);
        outb[(size_t)c * NPIX] = acc;
    }
}

// =========================================================================
static size_t align256(size_t x) { return (x + 255) & ~(size_t)255; }

static size_t region_bytes(int ch) {
    size_t region = align256((size_t)ch * 4 * NH1 * 4)
                  + align256((size_t)ch * 4 * NH2 * 4)
                  + align256((size_t)ch * 4 * NOUT * 4);
    size_t fftmin = 67108864 + 4096;   // guide Y-half 64MiB / Zc+Yi 64MiB
    if (region < fftmin) region = fftmin;
    return region;
}

static size_t plan_bytes(int ch) {
    size_t t = align256(region_bytes(ch));
    t += align256((size_t)Bn * FD * FH * FW * 4) * 2;   // featM, featP
    t += align256((size_t)Bn * GD * GH * GW * 4) * 2;   // guideM, guideP
    t += align256((size_t)Bn * 32 * NPIX * 4);          // phares (magres = d_out)
    t += align256((size_t)131072 * 2) * 2;              // w1t a/p
    t += align256((size_t)65536 * 2) * 2;               // w2t a/p
    t += align256((size_t)256 * 8) * 2;                 // relw a/p
    t += align256((size_t)NPIX * 4 * 4);                // idxb
    t += align256((size_t)NPIX * 4 * 8);                // relb
    t += align256(32768) + align256(131072);            // B1f, B1g
    t += align256(65536) + align256(262144);            // A2f, A2g
    t += align256(262144) + align256(262144);           // iB1, iA2
    return t;
}

extern "C" void kernel_launch(void* const* d_in, const int* in_sizes, int n_in,
                              void* d_out, int out_size, void* d_ws, size_t ws_size,
                              hipStream_t stream) {
    const float* feat  = (const float*)d_in[0];
    const float* coord = (const float*)d_in[1];
    const float* guide = (const float*)d_in[2];
    const float* aw1 = (const float*)d_in[3];
    const float* ab1 = (const float*)d_in[4];
    const float* aw2 = (const float*)d_in[5];
    const float* ab2 = (const float*)d_in[6];
    const float* aw3 = (const float*)d_in[7];
    const float* ab3 = (const float*)d_in[8];
    const float* pw1 = (const float*)d_in[9];
    const float* pb1 = (const float*)d_in[10];
    const float* pw2 = (const float*)d_in[11];
    const float* pb2 = (const float*)d_in[12];
    const float* pw3 = (const float*)d_in[13];
    const float* pb3 = (const float*)d_in[14];
    float* out = (float*)d_out;

    int ch = 0;
    const int cands[3] = {16384, 8192, 4096};
    for (int i = 0; i < 3; i++)
        if (plan_bytes(cands[i]) <= ws_size) { ch = cands[i]; break; }
    if (ch == 0) return;   // diagnostic: output stays poisoned, no fault
    const int nchk = (int)(ROWS / ch);

    char* ws = (char*)d_ws;
    size_t off = 0;
    auto alloc = [&](size_t bytes) -> void* {
        void* p = ws + off;
        off += align256(bytes);
        return p;
    };
    size_t region = region_bytes(ch);
    char*   rbase  = (char*)alloc(region);
    // region aliases (disjoint lifetimes):
    //   fwd FFT:  Yf (33.5MB) / Yg half (64MB)
    //   MLP:      H1c | H2c | predsC
    //   inv FFT:  Zc (32MB) | Yi (32MB)
    __bf16* Yf     = (__bf16*)rbase;
    __bf16* Yg     = (__bf16*)rbase;
    float*  H1c    = (float*)rbase;
    float*  H2c    = (float*)(rbase + align256((size_t)ch * 4 * NH1 * 4));
    float*  predsC = (float*)(rbase + align256((size_t)ch * 4 * NH1 * 4)
                                    + align256((size_t)ch * 4 * NH2 * 4));
    float*  Zc     = (float*)rbase;
    __bf16* Yi     = (__bf16*)(rbase + 33554432);
    float*  featM  = (float*)alloc((size_t)Bn * FD * FH * FW * 4);
    float*  featP  = (float*)alloc((size_t)Bn * FD * FH * FW * 4);
    float*  guideM = (float*)alloc((size_t)Bn * GD * GH * GW * 4);
    float*  guideP = (float*)alloc((size_t)Bn * GD * GH * GW * 4);
    float*  phares = (float*)alloc((size_t)Bn * 32 * NPIX * 4);
    float*  magres = out;   // alias: fully consumed by k_prep_zc before out written
    __bf16* w1ta   = (__bf16*)alloc((size_t)131072 * 2);
    __bf16* w1tp   = (__bf16*)alloc((size_t)131072 * 2);
    __bf16* w2ta   = (__bf16*)alloc((size_t)65536 * 2);
    __bf16* w2tp   = (__bf16*)alloc((size_t)65536 * 2);
    float2* relwa  = (float2*)alloc((size_t)256 * 8);
    float2* relwp  = (float2*)alloc((size_t)256 * 8);
    int*    idxb   = (int*)alloc((size_t)NPIX * 4 * 4);
    float2* relb   = (float2*)alloc((size_t)NPIX * 4 * 8);
    __bf16* B1f    = (__bf16*)alloc(32768);
    __bf16* B1g    = (__bf16*)alloc(131072);
    __bf16* A2f    = (__bf16*)alloc(65536);
    __bf16* A2g    = (__bf16*)alloc(262144);
    __bf16* iB1    = (__bf16*)alloc(262144);
    __bf16* iA2    = (__bf16*)alloc(262144);

    // ---- prep
    k_prep_w1<<<(256 * 256 + TPB - 1) / TPB, TPB, 0, stream>>>(aw1, w1ta, relwa);
    k_prep_w1<<<(256 * 256 + TPB - 1) / TPB, TPB, 0, stream>>>(pw1, w1tp, relwp);
    k_prep_w2<<<(256 * 128 + TPB - 1) / TPB, TPB, 0, stream>>>(aw2, w2ta);
    k_prep_w2<<<(256 * 128 + TPB - 1) / TPB, TPB, 0, stream>>>(pw2, w2tp);
    k_meta<<<(NPIX * 4 + TPB - 1) / TPB, TPB, 0, stream>>>(coord, idxb, relb);
    k_prep_fftmat<<<(64 * 128 + TPB - 1) / TPB, TPB, 0, stream>>>(0, 64, B1f);
    k_prep_fftmat<<<(128 * 256 + TPB - 1) / TPB, TPB, 0, stream>>>(0, 128, B1g);
    k_prep_fftmat<<<(128 * 128 + TPB - 1) / TPB, TPB, 0, stream>>>(1, 64, A2f);
    k_prep_fftmat<<<(256 * 256 + TPB - 1) / TPB, TPB, 0, stream>>>(1, 128, A2g);
    k_prep_fftmat<<<(256 * 256 + TPB - 1) / TPB, TPB, 0, stream>>>(2, 128, iB1);
    k_prep_fftmat<<<(256 * 256 + TPB - 1) / TPB, TPB, 0, stream>>>(3, 128, iA2);

    // ---- forward FFT: feat (1024 imgs 64x64), all-MFMA
    k_fft_p1<64, 64, 64><<<dim3(512, 1), TPB, 0, stream>>>(feat, B1f, Yf);
    k_fft_p2<64, 64, 1><<<dim3(512, 1), TPB, 0, stream>>>(A2f, Yf, featM, featP);
    // ---- forward FFT: guide (1024 imgs 128x128), 2 halves of 512 imgs
    for (int h = 0; h < 2; h++) {
        size_t ofs = (size_t)h * 512 * NPIX;
        k_fft_p1<128, 128, 128><<<dim3(512, 2), TPB, 0, stream>>>(
            guide + ofs, B1g, Yg);
        k_fft_p2<128, 128, 0><<<dim3(512, 2), TPB, 0, stream>>>(
            A2g, Yg, guideM + ofs, guideP + ofs);
    }

    // ---- two MLP branches (mag with a_*, pha with p_*), row-chunked
    for (int br = 0; br < 2; br++) {
        const float*  fX   = br ? featP  : featM;
        const float*  gX   = br ? guideP : guideM;
        const __bf16* w1t  = br ? w1tp : w1ta;
        const float2* relw = br ? relwp : relwa;
        const float*  b1   = br ? pb1 : ab1;
        const __bf16* w2t  = br ? w2tp : w2ta;
        const float*  b2   = br ? pb2 : ab2;
        const float*  w3   = br ? pw3 : aw3;
        const float*  b3   = br ? pb3 : ab3;
        float* resb = br ? phares : magres;
        for (int c = 0; c < nchk; c++) {
            int row0 = c * ch;
            k_gemm1_mfma<<<dim3(ch / 128, 2, 4), TPB, 0, stream>>>(
                fX, gX, idxb, relb, row0, ch, w1t, relw, b1, H1c);
            k_gemm2_mfma<<<dim3(ch / 128, 1, 4), TPB, 0, stream>>>(
                H1c, w2t, b2, H2c, ch);
            k_gemm<64, 64, 128, 33, false><<<dim3(ch / 64, 1, 4), TPB, 0, stream>>>(
                H2c, w3, b3, predsC, ch);
            k_combine<<<ch / TPB, TPB, 0, stream>>>(predsC, row0, ch, resb);
        }
    }

    // ---- inverse FFT (256 imgs 128x128) + abs, all-MFMA
    k_prep_zc<<<(256 * NPIX) / TPB, TPB, 0, stream>>>(magres, phares, Zc);
    k_fft_p1<256, 128, 128><<<dim3(256, 2), TPB, 0, stream>>>(Zc, iB1, Yi);
    k_fft_p2<128, 128, 2><<<dim3(256, 2), TPB, 0, stream>>>(iA2, Yi, out, nullptr);
}

// Round 10
// 2998.026 us; speedup vs baseline: 1.8942x; 1.0387x over previous
//
#include <hip/hip_runtime.h>
#include <cmath>

#define TPB 256

static constexpr int   Bn   = 8;
static constexpr int   GH   = 128, GW = 128;
static constexpr int   NPIX = GH * GW;          // 16384
static constexpr long  ROWS = (long)Bn * NPIX;  // 131072
static constexpr int   NH1  = 256, NH2 = 128, NOUT = 33;
static constexpr float TWO_PI = 6.28318530717958647692f;

typedef __attribute__((ext_vector_type(8))) __bf16 bf16x8;
typedef __attribute__((ext_vector_type(4))) float  f32x4;

// ---------------- gather metadata per (pixel, offset) -------------------
__global__ __launch_bounds__(TPB)
void k_meta(const float* __restrict__ coord, int* __restrict__ idxb,
            float2* __restrict__ relb) {
    int t = blockIdx.x * TPB + threadIdx.x;
    if (t >= NPIX * 4) return;
    int pix = t >> 2, o = t & 3;
    float cy = coord[pix * 2 + 0], cx = coord[pix * 2 + 1];
    float vx = (o < 2) ? -1.f : 1.f;       // ref loop order: vx outer, vy inner
    float vy = (o & 1) ? 1.f : -1.f;
    float cyo = cy + vx / 64.f, cxo = cx + vy / 64.f;
    float fy = rintf(((cyo + 1.f) * 64.f - 1.f) * 0.5f);
    float fx = rintf(((cxo + 1.f) * 64.f - 1.f) * 0.5f);
    bool valid = (fy >= 0.f) && (fy < 64.f) && (fx >= 0.f) && (fx < 64.f);
    int iy = min(max((int)fy, 0), 63), ix = min(max((int)fx, 0), 63);
    float qcy = valid ? (-1.f + (2.f * iy + 1.f) / 64.f) : 0.f;
    float qcx = valid ? (-1.f + (2.f * ix + 1.f) / 64.f) : 0.f;
    relb[t] = make_float2((cy - qcy) * 64.f, (cx - qcx) * 64.f);
    idxb[t] = valid ? (iy * 64 + ix) : -1;
}

// ---------------- weight prep: split-bf16 slabs --------------------------
// w1 (258x256) -> w1f (k<128) and w1g (k 128..255), each
// [nb2][st4][hl2][kb4][nl128][j8]; relw[n] = rows 256,257.
__global__ __launch_bounds__(TPB)
void k_prep_w1split(const float* __restrict__ w1, __bf16* __restrict__ w1f,
                    __bf16* __restrict__ w1g, float2* __restrict__ relw) {
    int i = blockIdx.x * TPB + threadIdx.x;
    if (i < 256) relw[i] = make_float2(w1[256 * 256 + i], w1[257 * 256 + i]);
    if (i >= 256 * 256) return;
    int k = i >> 8, n = i & 255;
    float v = w1[k * 256 + n];
    __bf16 h = (__bf16)v;
    __bf16 lo = (__bf16)(v - (float)h);
    int part = k >> 7, kl = k & 127;
    int nb = n >> 7, nl = n & 127, st = kl >> 5, kb = (kl >> 3) & 3, j = kl & 7;
    __bf16* dst = part ? w1g : w1f;
    size_t base = (size_t)(nb * 4 + st) * 8192 + kb * 1024 + nl * 8 + j;
    dst[base] = h;
    dst[base + 4096] = lo;
}

// w2 (256x128) -> [st8][hl2][kb4][n128][j8]
__global__ __launch_bounds__(TPB)
void k_prep_w2(const float* __restrict__ w2, __bf16* __restrict__ w2t) {
    int i = blockIdx.x * TPB + threadIdx.x;
    if (i >= 256 * 128) return;
    int k = i >> 7, n = i & 127;
    float v = w2[k * 128 + n];
    __bf16 h = (__bf16)v;
    __bf16 lo = (__bf16)(v - (float)h);
    int st = k >> 5, kb = (k >> 3) & 3, j = k & 7;
    size_t slab = (size_t)st * 8192;
    w2t[slab + 0    + kb * 1024 + n * 8 + j] = h;
    w2t[slab + 4096 + kb * 1024 + n * 8 + j] = lo;
}

// w3 (128x33) -> [st4][hl2][kb4][n48][j8], zero-padded n>=33
__global__ __launch_bounds__(TPB)
void k_prep_w3(const float* __restrict__ w3, __bf16* __restrict__ w3t) {
    int i = blockIdx.x * TPB + threadIdx.x;
    if (i >= 128 * 48) return;
    int k = i / 48, n = i - k * 48;
    float v = (n < 33) ? w3[k * 33 + n] : 0.f;
    __bf16 h = (__bf16)v;
    __bf16 lo = (__bf16)(v - (float)h);
    int st = k >> 5, kb = (k >> 3) & 3, j = k & 7;
    size_t base = (size_t)st * 3072 + kb * 384 + n * 8 + j;
    w3t[base] = h;
    w3t[base + 1536] = lo;
}

// ---------------- forward DFT pass-1 const matrix (A-type slab) ----------
// rows m = pl*P + v (0..2P-1), cols k = x (0..P-1):
// val = pl? -sin(2pi x v/P) : cos(2pi x v/P).  [mb][st][hl][kb][ml][j]
__global__ __launch_bounds__(TPB)
void k_prep_fftA1(int P, __bf16* __restrict__ outm) {
    int i = blockIdx.x * TPB + threadIdx.x;
    if (i >= 2 * P * P) return;
    int m = i / P, x = i - m * P;
    int pl = (m >= P) ? 1 : 0;
    int vv = m - pl * P;
    int xv = (x * vv) % P;
    float s, c; sincosf(TWO_PI * (float)xv / (float)P, &s, &c);
    float val = pl ? -s : c;
    __bf16 h = (__bf16)val;
    __bf16 lo = (__bf16)(val - (float)h);
    int mb = m >> 7, ml = m & 127;
    int ST = P >> 5;
    int st = x >> 5, kb = (x >> 3) & 3, j = x & 7;
    size_t base = (size_t)(mb * ST + st) * 8192 + kb * 1024 + ml * 8 + j;
    outm[base] = h;
    outm[base + 4096] = lo;
}

// ---------------- legacy DFT const prep (modes 1/2/3 used) ---------------
__global__ __launch_bounds__(TPB)
void k_prep_fftmat(int mode, int P, __bf16* __restrict__ outm) {
    int R, C, ST;
    bool Atype;
    if (mode == 0)      { R = P;   C = 2*P; ST = P >> 5; Atype = false; }
    else if (mode == 1) { R = 2*P; C = 2*P; ST = P >> 4; Atype = true;  }
    else                { R = 256; C = 256; ST = 8;      Atype = (mode == 3); }
    int i = blockIdx.x * TPB + threadIdx.x;
    if (i >= R * C) return;
    int r = i / C, c = i % C;
    float s, co, val;
    if (mode == 0) {
        int pl = (c >= P) ? 1 : 0, v = c - pl * P;
        int kv = (r * v) % P;
        sincosf(TWO_PI * (float)kv / (float)P, &s, &co);
        val = pl ? -s : co;
    } else if (mode == 1) {
        int u = r >> 1, p = r & 1;
        int pl = (c >= P) ? 1 : 0, y = c - pl * P;
        int uy = (u * y) % P;
        sincosf(TWO_PI * (float)uy / (float)P, &s, &co);
        val = (p == 0) ? (pl ? s : co) : (pl ? co : -s);
    } else if (mode == 2) {
        int v = r >> 1, q = r & 1;
        int pl = c >> 7, x = c & 127;
        int vx = (v * x) & 127;
        sincosf(TWO_PI * (float)vx / 128.f, &s, &co);
        val = (q == 0) ? (pl ? s : co) : (pl ? co : -s);
    } else {
        int y = r >> 1, p = r & 1;
        int pl = c >> 7, u = c & 127;
        int uy = (u * y) & 127;
        sincosf(TWO_PI * (float)uy / 128.f, &s, &co);
        val = (p == 0) ? (pl ? -s : co) : (pl ? co : s);
    }
    int blk, lin, kidx;
    if (Atype) { blk = r >> 7; lin = r & 127; kidx = c; }
    else       { blk = c >> 7; lin = c & 127; kidx = r; }
    int st = kidx >> 5, kb = (kidx >> 3) & 3, j = kidx & 7;
    __bf16 h = (__bf16)val;
    __bf16 lo = (__bf16)(val - (float)h);
    size_t base = (((size_t)blk * ST + st) * 2) * 4096 + (size_t)kb * 1024 + lin * 8 + j;
    outm[base] = h;
    outm[base + 4096] = lo;
}

// ---------------- fwd FFT pass 1 (x-transform, N = channels) -------------
// block (brel, y, mb): out Z1[brel][v][k'=pl*P+y][c] fp32, M=(pl,v), K=x.
template <int P>
__global__ __launch_bounds__(TPB)
void k_fft1(const float* __restrict__ in, const __bf16* __restrict__ A1,
            float* __restrict__ Z1, int b0) {
    constexpr int LOG2P = (P == 64) ? 6 : 7;
    constexpr int ST = P / 32;
    __shared__ __align__(16) __bf16 As2[8192];   // const [hl][kb][m128][j8]
    __shared__ __align__(16) __bf16 Bs2[8192];   // data  [hl][kb][c128][j8]
    int t = threadIdx.x;
    int bid = blockIdx.x;
    int brel = bid >> LOG2P, y = bid & (P - 1);
    int b = b0 + brel;
    int mb = blockIdx.y;
    int w = t >> 6, l = t & 63;
    int wr = w >> 1, wc = w & 1;
    int lr = l & 15, lk = l >> 4;
    int cs = t >> 1, kh = t & 1;     // staging: channel, k-half
    f32x4 acc[4][4];
    #pragma unroll
    for (int i = 0; i < 4; i++)
        #pragma unroll
        for (int j = 0; j < 4; j++) acc[i][j] = f32x4{0.f, 0.f, 0.f, 0.f};
    for (int st = 0; st < ST; st++) {
        const float4* dp = (const float4*)&in[((size_t)(b * 128 + cs) * P + y) * P
                                             + st * 32 + kh * 16];
        float4 va4[4];
        #pragma unroll
        for (int i = 0; i < 4; i++) va4[i] = dp[i];
        const float4* asl = (const float4*)(A1 + (size_t)(mb * ST + st) * 8192);
        float4 av[4];
        #pragma unroll
        for (int i = 0; i < 4; i++) av[i] = asl[i * 256 + t];
        __syncthreads();
        {
            const float* va = (const float*)&va4[0];
            __bf16 h8[16], l8[16];
            #pragma unroll
            for (int j = 0; j < 16; j++) {
                __bf16 h = (__bf16)va[j];
                h8[j] = h;
                l8[j] = (__bf16)(va[j] - (float)h);
            }
            int kb0 = kh * 2;
            *(bf16x8*)&Bs2[(kb0    ) * 1024 + cs * 8] = *(bf16x8*)&h8[0];
            *(bf16x8*)&Bs2[(kb0 + 1) * 1024 + cs * 8] = *(bf16x8*)&h8[8];
            *(bf16x8*)&Bs2[4096 + (kb0    ) * 1024 + cs * 8] = *(bf16x8*)&l8[0];
            *(bf16x8*)&Bs2[4096 + (kb0 + 1) * 1024 + cs * 8] = *(bf16x8*)&l8[8];
            float4* ad = (float4*)&As2[0];
            #pragma unroll
            for (int i = 0; i < 4; i++) ad[i * 256 + t] = av[i];
        }
        __syncthreads();
        bf16x8 ah[4], al[4], bh[4], blo[4];
        #pragma unroll
        for (int mf = 0; mf < 4; mf++) {
            int m = wr * 64 + mf * 16 + lr;
            ah[mf] = *(const bf16x8*)&As2[lk * 1024 + m * 8];
            al[mf] = *(const bf16x8*)&As2[4096 + lk * 1024 + m * 8];
        }
        #pragma unroll
        for (int nf = 0; nf < 4; nf++) {
            int n = wc * 64 + nf * 16 + lr;
            bh[nf]  = *(const bf16x8*)&Bs2[lk * 1024 + n * 8];
            blo[nf] = *(const bf16x8*)&Bs2[4096 + lk * 1024 + n * 8];
        }
        #pragma unroll
        for (int mf = 0; mf < 4; mf++)
            #pragma unroll
            for (int nf = 0; nf < 4; nf++) {
                acc[mf][nf] = __builtin_amdgcn_mfma_f32_16x16x32_bf16(ah[mf], bh[nf],  acc[mf][nf], 0, 0, 0);
                acc[mf][nf] = __builtin_amdgcn_mfma_f32_16x16x32_bf16(ah[mf], blo[nf], acc[mf][nf], 0, 0, 0);
                acc[mf][nf] = __builtin_amdgcn_mfma_f32_16x16x32_bf16(al[mf], bh[nf],  acc[mf][nf], 0, 0, 0);
            }
    }
    #pragma unroll
    for (int nf = 0; nf < 4; nf++) {
        int c = wc * 64 + nf * 16 + lr;
        #pragma unroll
        for (int mf = 0; mf < 4; mf++)
            #pragma unroll
            for (int r = 0; r < 4; r++) {
                int m = mb * 128 + wr * 64 + mf * 16 + lk * 4 + r;
                int pl = m >> LOG2P, v = m & (P - 1);
                int kp = pl * P + y;
                Z1[(((size_t)brel * P + v) * (2 * P) + kp) * 128 + c] = acc[mf][nf][r];
            }
    }
}

// ---------------- fwd FFT pass 2 (y-transform) + mag/pha (transposed) ----
// block (brel, v, mb): A = const (2u+p)x(pl,y); B = Z1[brel][v] (fp32,
// split in staging); out mag/pha -> T arrays [b][pix][c].
template <int P>
__global__ __launch_bounds__(TPB)
void k_fft2(const __bf16* __restrict__ A2, const float* __restrict__ Z1,
            float* __restrict__ outM, float* __restrict__ outP, int b0) {
    constexpr int LOG2P = (P == 64) ? 6 : 7;
    constexpr int ST2 = P / 16;      // K = 2P
    __shared__ __align__(16) __bf16 As2[8192];
    __shared__ __align__(16) __bf16 Bs2[8192];
    int t = threadIdx.x;
    int bid = blockIdx.x;
    int brel = bid >> LOG2P, v = bid & (P - 1);
    int b = b0 + brel;
    int mb = blockIdx.y;
    int w = t >> 6, l = t & 63;
    int wr = w >> 1, wc = w & 1;
    int lr = l & 15, lk = l >> 4;
    int kq = t >> 3, cq = (t & 7) * 16;  // staging: k-off (0..31), c-base
    f32x4 acc[4][4];
    #pragma unroll
    for (int i = 0; i < 4; i++)
        #pragma unroll
        for (int j = 0; j < 4; j++) acc[i][j] = f32x4{0.f, 0.f, 0.f, 0.f};
    size_t zbase = ((size_t)brel * P + v) * (2 * P) * 128;
    for (int st = 0; st < ST2; st++) {
        const float4* zp = (const float4*)&Z1[zbase + (size_t)(st * 32 + kq) * 128 + cq];
        float4 z4[4];
        #pragma unroll
        for (int i = 0; i < 4; i++) z4[i] = zp[i];
        const float4* asl = (const float4*)(A2 + (size_t)(mb * ST2 + st) * 8192);
        float4 av[4];
        #pragma unroll
        for (int i = 0; i < 4; i++) av[i] = asl[i * 256 + t];
        __syncthreads();
        {
            const float* zz = (const float*)&z4[0];
            int kb = kq >> 3, j = kq & 7;
            #pragma unroll
            for (int i = 0; i < 16; i++) {
                float val = zz[i];
                __bf16 h = (__bf16)val;
                __bf16 lo = (__bf16)(val - (float)h);
                int c = cq + i;
                Bs2[kb * 1024 + c * 8 + j] = h;
                Bs2[4096 + kb * 1024 + c * 8 + j] = lo;
            }
            float4* ad = (float4*)&As2[0];
            #pragma unroll
            for (int i = 0; i < 4; i++) ad[i * 256 + t] = av[i];
        }
        __syncthreads();
        bf16x8 ah[4], al[4], bh[4], blo[4];
        #pragma unroll
        for (int mf = 0; mf < 4; mf++) {
            int m = wr * 64 + mf * 16 + lr;
            ah[mf] = *(const bf16x8*)&As2[lk * 1024 + m * 8];
            al[mf] = *(const bf16x8*)&As2[4096 + lk * 1024 + m * 8];
        }
        #pragma unroll
        for (int nf = 0; nf < 4; nf++) {
            int n = wc * 64 + nf * 16 + lr;
            bh[nf]  = *(const bf16x8*)&Bs2[lk * 1024 + n * 8];
            blo[nf] = *(const bf16x8*)&Bs2[4096 + lk * 1024 + n * 8];
        }
        #pragma unroll
        for (int mf = 0; mf < 4; mf++)
            #pragma unroll
            for (int nf = 0; nf < 4; nf++) {
                acc[mf][nf] = __builtin_amdgcn_mfma_f32_16x16x32_bf16(ah[mf], bh[nf],  acc[mf][nf], 0, 0, 0);
                acc[mf][nf] = __builtin_amdgcn_mfma_f32_16x16x32_bf16(ah[mf], blo[nf], acc[mf][nf], 0, 0, 0);
                acc[mf][nf] = __builtin_amdgcn_mfma_f32_16x16x32_bf16(al[mf], bh[nf],  acc[mf][nf], 0, 0, 0);
            }
    }
    #pragma unroll
    for (int nf = 0; nf < 4; nf++) {
        int c = wc * 64 + nf * 16 + lr;
        #pragma unroll
        for (int mf = 0; mf < 4; mf++) {
            int mlocb = mb * 128 + wr * 64 + mf * 16 + lk * 4;
            #pragma unroll
            for (int rp = 0; rp < 4; rp += 2) {
                float re = acc[mf][nf][rp], im = acc[mf][nf][rp + 1];
                int u = (mlocb + rp) >> 1;
                size_t oi = ((size_t)b * (P * P) + u * P + v) * 128 + c;
                outM[oi] = sqrtf(re * re + im * im);
                outP[oi] = atan2f(im, re);
            }
        }
    }
}

// ---------------- inverse DFT pass 1 (legacy, bf16 slab) -----------------
template <int KTOT, int SW, int HROWS>
__global__ __launch_bounds__(TPB)
void k_fft_p1(const float* __restrict__ A, const __bf16* __restrict__ Bc,
              __bf16* __restrict__ Yslab) {
    constexpr int ST     = KTOT / 32;
    constexpr int LOG2H  = (HROWS == 64) ? 6 : 7;
    constexpr int CHUNK  = 64 * SW;
    constexpr int ST2T   = HROWS / 16;
    constexpr int IMGSLB = ST2T * CHUNK;
    __shared__ __align__(16) __bf16 As2[2][4][128][8];
    __shared__ __align__(16) __bf16 Bs2[8192];
    int t = threadIdx.x;
    int bm0 = blockIdx.x * 128;
    int nb  = blockIdx.y;
    int w = t >> 6, l = t & 63;
    int wr = w >> 1, wc = w & 1;
    int lr = l & 15, lk = l >> 4;
    int am = t >> 1, kh = t & 1;
    f32x4 acc[4][4];
    #pragma unroll
    for (int i = 0; i < 4; i++)
        #pragma unroll
        for (int j = 0; j < 4; j++) acc[i][j] = f32x4{0.f, 0.f, 0.f, 0.f};
    for (int st = 0; st < ST; st++) {
        const float* arow = A + (size_t)(bm0 + am) * KTOT + st * 32 + kh * 16;
        float4 va4[4];
        #pragma unroll
        for (int i = 0; i < 4; i++) va4[i] = ((const float4*)arow)[i];
        const float4* wsl = (const float4*)(Bc + ((size_t)nb * ST + st) * 8192);
        float4 bv[4];
        #pragma unroll
        for (int i = 0; i < 4; i++) bv[i] = wsl[i * 256 + t];
        __syncthreads();
        {
            const float* va = (const float*)&va4[0];
            __bf16 h8[16], l8[16];
            #pragma unroll
            for (int j = 0; j < 16; j++) {
                __bf16 h = (__bf16)va[j];
                h8[j] = h;
                l8[j] = (__bf16)(va[j] - (float)h);
            }
            int kb0 = kh * 2;
            *(bf16x8*)&As2[0][kb0][am][0]     = *(bf16x8*)&h8[0];
            *(bf16x8*)&As2[0][kb0 + 1][am][0] = *(bf16x8*)&h8[8];
            *(bf16x8*)&As2[1][kb0][am][0]     = *(bf16x8*)&l8[0];
            *(bf16x8*)&As2[1][kb0 + 1][am][0] = *(bf16x8*)&l8[8];
            float4* bd = (float4*)&Bs2[0];
            #pragma unroll
            for (int i = 0; i < 4; i++) bd[i * 256 + t] = bv[i];
        }
        __syncthreads();
        bf16x8 ah[4], al[4], bh[4], blo[4];
        #pragma unroll
        for (int mf = 0; mf < 4; mf++) {
            int m = wr * 64 + mf * 16 + lr;
            ah[mf] = *(const bf16x8*)&As2[0][lk][m][0];
            al[mf] = *(const bf16x8*)&As2[1][lk][m][0];
        }
        #pragma unroll
        for (int nf = 0; nf < 4; nf++) {
            int n = wc * 64 + nf * 16 + lr;
            bh[nf]  = *(const bf16x8*)&Bs2[(size_t)lk * 1024 + n * 8];
            blo[nf] = *(const bf16x8*)&Bs2[4096 + (size_t)lk * 1024 + n * 8];
        }
        #pragma unroll
        for (int mf = 0; mf < 4; mf++)
            #pragma unroll
            for (int nf = 0; nf < 4; nf++) {
                acc[mf][nf] = __builtin_amdgcn_mfma_f32_16x16x32_bf16(ah[mf], bh[nf],  acc[mf][nf], 0, 0, 0);
                acc[mf][nf] = __builtin_amdgcn_mfma_f32_16x16x32_bf16(ah[mf], blo[nf], acc[mf][nf], 0, 0, 0);
                acc[mf][nf] = __builtin_amdgcn_mfma_f32_16x16x32_bf16(al[mf], bh[nf],  acc[mf][nf], 0, 0, 0);
            }
    }
    #pragma unroll
    for (int nf = 0; nf < 4; nf++) {
        int Cg = nb * 128 + wc * 64 + nf * 16 + lr;
        int plane = Cg / SW;
        int v = Cg % SW;
        #pragma unroll
        for (int mf = 0; mf < 4; mf++)
            #pragma unroll
            for (int r = 0; r < 4; r++) {
                int rloc = wr * 64 + mf * 16 + lk * 4 + r;
                int grow = bm0 + rloc;
                int img = grow >> LOG2H;
                int y = grow & (HROWS - 1);
                int kp = plane * HROWS + y;
                int st2 = kp >> 5, kb2 = (kp >> 3) & 3, j2 = kp & 7;
                size_t a = (size_t)img * IMGSLB + (size_t)st2 * CHUNK
                         + (size_t)kb2 * (SW * 8) + v * 8 + j2;
                float val = acc[mf][nf][r];
                __bf16 h = (__bf16)val;
                Yslab[a] = h;
                Yslab[a + 32 * SW] = (__bf16)(val - (float)h);
            }
    }
}

// ---------------- inverse DFT pass 2 + abs (legacy) ----------------------
template <int HROWS, int SW, int EPI>
__global__ __launch_bounds__(TPB)
void k_fft_p2(const __bf16* __restrict__ Ac, const __bf16* __restrict__ Yslab,
              float* __restrict__ out0, float* __restrict__ out1) {
    constexpr int ST2    = HROWS / 16;
    constexpr int CHUNK  = 64 * SW;
    constexpr int IMGSLB = ST2 * CHUNK;
    __shared__ __align__(16) __bf16 As2[2][4][128][8];
    __shared__ __align__(16) __bf16 Bs2[8192];
    int t = threadIdx.x;
    int imgx = blockIdx.x;
    int mb   = blockIdx.y;
    int w = t >> 6, l = t & 63;
    int wr = w >> 1, wc = w & 1;
    int lr = l & 15, lk = l >> 4;
    f32x4 acc[4][4];
    #pragma unroll
    for (int i = 0; i < 4; i++)
        #pragma unroll
        for (int j = 0; j < 4; j++) acc[i][j] = f32x4{0.f, 0.f, 0.f, 0.f};
    for (int st = 0; st < ST2; st++) {
        const float4* asl = (const float4*)(Ac + ((size_t)mb * ST2 + st) * 8192);
        float4 av[4];
        #pragma unroll
        for (int i = 0; i < 4; i++) av[i] = asl[i * 256 + t];
        const float4* bsl = (const float4*)(Yslab
            + (size_t)imgx * IMGSLB + (size_t)st * CHUNK);
        float4 bv[4];
        #pragma unroll
        for (int i = 0; i < 4; i++) bv[i] = bsl[i * 256 + t];
        __syncthreads();
        {
            float4* ad = (float4*)&As2[0][0][0][0];
            #pragma unroll
            for (int i = 0; i < 4; i++) ad[i * 256 + t] = av[i];
            float4* bd = (float4*)&Bs2[0];
            #pragma unroll
            for (int i = 0; i < 4; i++) bd[i * 256 + t] = bv[i];
        }
        __syncthreads();
        bf16x8 ah[4], al[4], bh[4], blo[4];
        #pragma unroll
        for (int mf = 0; mf < 4; mf++) {
            int m = wr * 64 + mf * 16 + lr;
            ah[mf] = *(const bf16x8*)&As2[0][lk][m][0];
            al[mf] = *(const bf16x8*)&As2[1][lk][m][0];
        }
        #pragma unroll
        for (int nf = 0; nf < 4; nf++) {
            int n = wc * 64 + nf * 16 + lr;
            bh[nf]  = *(const bf16x8*)&Bs2[(size_t)lk * 1024 + n * 8];
            blo[nf] = *(const bf16x8*)&Bs2[4096 + (size_t)lk * 1024 + n * 8];
        }
        #pragma unroll
        for (int mf = 0; mf < 4; mf++)
            #pragma unroll
            for (int nf = 0; nf < 4; nf++) {
                acc[mf][nf] = __builtin_amdgcn_mfma_f32_16x16x32_bf16(ah[mf], bh[nf],  acc[mf][nf], 0, 0, 0);
                acc[mf][nf] = __builtin_amdgcn_mfma_f32_16x16x32_bf16(ah[mf], blo[nf], acc[mf][nf], 0, 0, 0);
                acc[mf][nf] = __builtin_amdgcn_mfma_f32_16x16x32_bf16(al[mf], bh[nf],  acc[mf][nf], 0, 0, 0);
            }
    }
    #pragma unroll
    for (int nf = 0; nf < 4; nf++) {
        int v = wc * 64 + nf * 16 + lr;
        #pragma unroll
        for (int mf = 0; mf < 4; mf++) {
            int mlocb = wr * 64 + mf * 16 + lk * 4;
            #pragma unroll
            for (int rp = 0; rp < 4; rp += 2) {
                float re = acc[mf][nf][rp], im = acc[mf][nf][rp + 1];
                int m = mb * 128 + mlocb + rp;
                int u = m >> 1;
                size_t oi = (size_t)imgx * 16384 + (size_t)u * 128 + v;
                out0[oi] = sqrtf(re * re + im * im) * (1.f / 16384.f);
            }
        }
    }
}

// ---------------- mag/pha -> interleaved complex -------------------------
__global__ __launch_bounds__(TPB)
void k_prep_zc(const float* __restrict__ mag, const float* __restrict__ pha,
               float* __restrict__ Zc) {
    int i = blockIdx.x * TPB + threadIdx.x;
    float m = mag[i], p = pha[i];
    float s, c; sincosf(p, &s, &c);
    Zc[2 * i]     = m * c;
    Zc[2 * i + 1] = m * s;
}

// ---------------- GEMM1 fused: guide GEMM once + 4 offset feat GEMMs -----
// BM=64, N=128 per block (nb grid). guide product kept in regs (gb) and
// reused as acc-init per offset. All A-loads contiguous from T arrays.
__global__ __launch_bounds__(TPB)
void k_gemm1f(const float* __restrict__ featT, const float* __restrict__ guideT,
              const int* __restrict__ idxb, const float2* __restrict__ relb,
              int row0, int ch,
              const __bf16* __restrict__ w1f, const __bf16* __restrict__ w1g,
              const float2* __restrict__ relw, const float* __restrict__ b1,
              float* __restrict__ H1c) {
    __shared__ __align__(16) __bf16 As2[4096];   // [hl2][kb4][r64][j8]
    __shared__ __align__(16) __bf16 Bs2[8192];   // [hl2][kb4][n128][j8]
    __shared__ int    sfo[4][64];
    __shared__ float2 srel[4][64];
    int t = threadIdx.x;
    int bm0 = blockIdx.x * 64;
    int nb  = blockIdx.y;
    {
        int o = t >> 6, r = t & 63;
        int grow = row0 + bm0 + r;
        int b = grow >> 14, pix = grow & 16383;
        int id = idxb[pix * 4 + o];
        sfo[o][r] = (id >= 0) ? (b * 4096 + id) : -1;
        srel[o][r] = relb[pix * 4 + o];
    }
    int w = t >> 6, l = t & 63;
    int wr = w >> 1, wc = w & 1;
    int lr = l & 15, lk = l >> 4;
    int rs = t & 63, kq = t >> 6;
    // bias/relw per column (hoisted)
    float bb[4]; float2 rw[4];
    #pragma unroll
    for (int nf = 0; nf < 4; nf++) {
        int col = nb * 128 + wc * 64 + nf * 16 + lr;
        bb[nf] = b1[col];
        rw[nf] = relw[col];
    }
    f32x4 acc[2][4], gb[2][4];
    #pragma unroll
    for (int i = 0; i < 2; i++)
        #pragma unroll
        for (int j = 0; j < 4; j++) acc[i][j] = f32x4{0.f, 0.f, 0.f, 0.f};
    __syncthreads();
    // ---- guide GEMM (K=128)
    size_t arowg = (size_t)(row0 + bm0 + rs) * 128;
    for (int st = 0; st < 4; st++) {
        const float4* ap = (const float4*)&guideT[arowg + st * 32 + kq * 8];
        float4 a0 = ap[0], a1 = ap[1];
        const float4* wsl = (const float4*)(w1g + (size_t)(nb * 4 + st) * 8192);
        float4 bv[4];
        #pragma unroll
        for (int i = 0; i < 4; i++) bv[i] = wsl[i * 256 + t];
        __syncthreads();
        {
            float va[8] = {a0.x, a0.y, a0.z, a0.w, a1.x, a1.y, a1.z, a1.w};
            __bf16 h8[8], l8[8];
            #pragma unroll
            for (int j = 0; j < 8; j++) {
                __bf16 h = (__bf16)va[j];
                h8[j] = h;
                l8[j] = (__bf16)(va[j] - (float)h);
            }
            *(bf16x8*)&As2[kq * 512 + rs * 8] = *(bf16x8*)&h8[0];
            *(bf16x8*)&As2[2048 + kq * 512 + rs * 8] = *(bf16x8*)&l8[0];
            float4* bd = (float4*)&Bs2[0];
            #pragma unroll
            for (int i = 0; i < 4; i++) bd[i * 256 + t] = bv[i];
        }
        __syncthreads();
        bf16x8 ah[2], al[2], bh[4], blo[4];
        #pragma unroll
        for (int mf = 0; mf < 2; mf++) {
            int m = wr * 32 + mf * 16 + lr;
            ah[mf] = *(const bf16x8*)&As2[lk * 512 + m * 8];
            al[mf] = *(const bf16x8*)&As2[2048 + lk * 512 + m * 8];
        }
        #pragma unroll
        for (int nf = 0; nf < 4; nf++) {
            int n = wc * 64 + nf * 16 + lr;
            bh[nf]  = *(const bf16x8*)&Bs2[lk * 1024 + n * 8];
            blo[nf] = *(const bf16x8*)&Bs2[4096 + lk * 1024 + n * 8];
        }
        #pragma unroll
        for (int mf = 0; mf < 2; mf++)
            #pragma unroll
            for (int nf = 0; nf < 4; nf++) {
                acc[mf][nf] = __builtin_amdgcn_mfma_f32_16x16x32_bf16(ah[mf], bh[nf],  acc[mf][nf], 0, 0, 0);
                acc[mf][nf] = __builtin_amdgcn_mfma_f32_16x16x32_bf16(ah[mf], blo[nf], acc[mf][nf], 0, 0, 0);
                acc[mf][nf] = __builtin_amdgcn_mfma_f32_16x16x32_bf16(al[mf], bh[nf],  acc[mf][nf], 0, 0, 0);
            }
    }
    #pragma unroll
    for (int i = 0; i < 2; i++)
        #pragma unroll
        for (int j = 0; j < 4; j++) gb[i][j] = acc[i][j];
    // ---- per-offset feat GEMM (K=128), acc init = gb
    for (int o = 0; o < 4; o++) {
        #pragma unroll
        for (int i = 0; i < 2; i++)
            #pragma unroll
            for (int j = 0; j < 4; j++) acc[i][j] = gb[i][j];
        int fo = sfo[o][rs];
        for (int st = 0; st < 4; st++) {
            float4 a0, a1;
            if (fo >= 0) {
                const float4* ap = (const float4*)&featT[(size_t)fo * 128 + st * 32 + kq * 8];
                a0 = ap[0]; a1 = ap[1];
            } else {
                a0 = make_float4(0.f, 0.f, 0.f, 0.f); a1 = a0;
            }
            const float4* wsl = (const float4*)(w1f + (size_t)(nb * 4 + st) * 8192);
            float4 bv[4];
            #pragma unroll
            for (int i = 0; i < 4; i++) bv[i] = wsl[i * 256 + t];
            __syncthreads();
            {
                float va[8] = {a0.x, a0.y, a0.z, a0.w, a1.x, a1.y, a1.z, a1.w};
                __bf16 h8[8], l8[8];
                #pragma unroll
                for (int j = 0; j < 8; j++) {
                    __bf16 h = (__bf16)va[j];
                    h8[j] = h;
                    l8[j] = (__bf16)(va[j] - (float)h);
                }
                *(bf16x8*)&As2[kq * 512 + rs * 8] = *(bf16x8*)&h8[0];
                *(bf16x8*)&As2[2048 + kq * 512 + rs * 8] = *(bf16x8*)&l8[0];
                float4* bd = (float4*)&Bs2[0];
                #pragma unroll
                for (int i = 0; i < 4; i++) bd[i * 256 + t] = bv[i];
            }
            __syncthreads();
            bf16x8 ah[2], al[2], bh[4], blo[4];
            #pragma unroll
            for (int mf = 0; mf < 2; mf++) {
                int m = wr * 32 + mf * 16 + lr;
                ah[mf] = *(const bf16x8*)&As2[lk * 512 + m * 8];
                al[mf] = *(const bf16x8*)&As2[2048 + lk * 512 + m * 8];
            }
            #pragma unroll
            for (int nf = 0; nf < 4; nf++) {
                int n = wc * 64 + nf * 16 + lr;
                bh[nf]  = *(const bf16x8*)&Bs2[lk * 1024 + n * 8];
                blo[nf] = *(const bf16x8*)&Bs2[4096 + lk * 1024 + n * 8];
            }
            #pragma unroll
            for (int mf = 0; mf < 2; mf++)
                #pragma unroll
                for (int nf = 0; nf < 4; nf++) {
                    acc[mf][nf] = __builtin_amdgcn_mfma_f32_16x16x32_bf16(ah[mf], bh[nf],  acc[mf][nf], 0, 0, 0);
                    acc[mf][nf] = __builtin_amdgcn_mfma_f32_16x16x32_bf16(ah[mf], blo[nf], acc[mf][nf], 0, 0, 0);
                    acc[mf][nf] = __builtin_amdgcn_mfma_f32_16x16x32_bf16(al[mf], bh[nf],  acc[mf][nf], 0, 0, 0);
                }
        }
        // epilogue for this offset
        #pragma unroll
        for (int nf = 0; nf < 4; nf++) {
            int col = nb * 128 + wc * 64 + nf * 16 + lr;
            #pragma unroll
            for (int mf = 0; mf < 2; mf++)
                #pragma unroll
                for (int r = 0; r < 4; r++) {
                    int rloc = wr * 32 + mf * 16 + lk * 4 + r;
                    float2 rr = srel[o][rloc];
                    float v = acc[mf][nf][r] + bb[nf] + rr.x * rw[nf].x + rr.y * rw[nf].y;
                    H1c[((size_t)o * ch + bm0 + rloc) * NH1 + col] = fmaxf(v, 0.f);
                }
        }
    }
}

// ---------------- GEMM2: H1 (fp32) x W2, split-bf16 MFMA (unchanged) -----
__global__ __launch_bounds__(TPB)
void k_gemm2_mfma(const float* __restrict__ A, const __bf16* __restrict__ w2t,
                  const float* __restrict__ b2, float* __restrict__ H2c, int ch) {
    __shared__ __align__(16) __bf16 As2[2][4][128][8];
    __shared__ __align__(16) __bf16 Bs2[8192];
    int t = threadIdx.x;
    int o = blockIdx.z;
    int bm0 = blockIdx.x * 128;
    int w = t >> 6, l = t & 63;
    int wr = w >> 1, wc = w & 1;
    int lr = l & 15, lk = l >> 4;
    int am = t >> 1, kh = t & 1;
    f32x4 acc[4][4];
    #pragma unroll
    for (int i = 0; i < 4; i++)
        #pragma unroll
        for (int j = 0; j < 4; j++) acc[i][j] = f32x4{0.f, 0.f, 0.f, 0.f};
    size_t arow = ((size_t)o * ch + bm0 + am) * NH1;
    for (int st = 0; st < 8; st++) {
        int k0 = st * 32;
        float4 va4[4];
        #pragma unroll
        for (int i = 0; i < 4; i++)
            va4[i] = *(const float4*)&A[arow + k0 + kh * 16 + i * 4];
        float4 bv[4];
        const float4* wsl = (const float4*)(w2t + (size_t)st * 8192);
        #pragma unroll
        for (int i = 0; i < 4; i++) bv[i] = wsl[i * 256 + t];
        __syncthreads();
        {
            const float* va = (const float*)&va4[0];
            __bf16 h8[16], l8[16];
            #pragma unroll
            for (int j = 0; j < 16; j++) {
                __bf16 h = (__bf16)va[j];
                h8[j] = h;
                l8[j] = (__bf16)(va[j] - (float)h);
            }
            int kb0 = kh * 2;
            *(bf16x8*)&As2[0][kb0][am][0]     = *(bf16x8*)&h8[0];
            *(bf16x8*)&As2[0][kb0 + 1][am][0] = *(bf16x8*)&h8[8];
            *(bf16x8*)&As2[1][kb0][am][0]     = *(bf16x8*)&l8[0];
            *(bf16x8*)&As2[1][kb0 + 1][am][0] = *(bf16x8*)&l8[8];
            float4* bd = (float4*)&Bs2[0];
            #pragma unroll
            for (int i = 0; i < 4; i++) bd[i * 256 + t] = bv[i];
        }
        __syncthreads();
        bf16x8 ah[4], al[4], bh[4], blo[4];
        #pragma unroll
        for (int mf = 0; mf < 4; mf++) {
            int m = wr * 64 + mf * 16 + lr;
            ah[mf] = *(const bf16x8*)&As2[0][lk][m][0];
            al[mf] = *(const bf16x8*)&As2[1][lk][m][0];
        }
        #pragma unroll
        for (int nf = 0; nf < 4; nf++) {
            int n = wc * 64 + nf * 16 + lr;
            bh[nf]  = *(const bf16x8*)&Bs2[(size_t)lk * 1024 + n * 8];
            blo[nf] = *(const bf16x8*)&Bs2[4096 + (size_t)lk * 1024 + n * 8];
        }
        #pragma unroll
        for (int mf = 0; mf < 4; mf++)
            #pragma unroll
            for (int nf = 0; nf < 4; nf++) {
                acc[mf][nf] = __builtin_amdgcn_mfma_f32_16x16x32_bf16(ah[mf], bh[nf],  acc[mf][nf], 0, 0, 0);
                acc[mf][nf] = __builtin_amdgcn_mfma_f32_16x16x32_bf16(ah[mf], blo[nf], acc[mf][nf], 0, 0, 0);
                acc[mf][nf] = __builtin_amdgcn_mfma_f32_16x16x32_bf16(al[mf], bh[nf],  acc[mf][nf], 0, 0, 0);
            }
    }
    #pragma unroll
    for (int nf = 0; nf < 4; nf++) {
        int col = wc * 64 + nf * 16 + lr;
        float bias = b2[col];
        #pragma unroll
        for (int mf = 0; mf < 4; mf++)
            #pragma unroll
            for (int r = 0; r < 4; r++) {
                int rloc = wr * 64 + mf * 16 + lk * 4 + r;
                float v = acc[mf][nf][r] + bias;
                H2c[((size_t)o * ch + bm0 + rloc) * NH2 + col] = fmaxf(v, 0.f);
            }
    }
}

// ---------------- fused GEMM3 (N=48 MFMA) + softmax-combine --------------
// BM=64 per block; o-loop internal; pred kept in regs; writes final res.
__global__ __launch_bounds__(TPB)
void k_g3c(const float* __restrict__ H2c, const __bf16* __restrict__ w3t,
           const float* __restrict__ b3, int row0, int ch,
           float* __restrict__ res) {
    __shared__ __align__(16) __bf16 As2[4096];   // [hl2][kb4][r64][j8]
    __shared__ __align__(16) __bf16 Bs3[3072];   // [hl2][kb4][n48][j8]
    __shared__ float p3s[4][64];
    int t = threadIdx.x;
    int bm0 = blockIdx.x * 64;
    int w = t >> 6, l = t & 63;
    int lr = l & 15, lk = l >> 4;
    int rs = t & 63, kq = t >> 6;
    f32x4 acc[4][3];
    #pragma unroll
    for (int o = 0; o < 4; o++)
        #pragma unroll
        for (int j = 0; j < 3; j++) acc[o][j] = f32x4{0.f, 0.f, 0.f, 0.f};
    #pragma unroll
    for (int o = 0; o < 4; o++) {
        for (int st = 0; st < 4; st++) {
            const float4* ap = (const float4*)&H2c[((size_t)o * ch + bm0 + rs) * NH2
                                                   + st * 32 + kq * 8];
            float4 a0 = ap[0], a1 = ap[1];
            const float4* wsl = (const float4*)(w3t + (size_t)st * 3072);
            float4 bv0 = wsl[t];
            float4 bv1;
            if (t < 128) bv1 = wsl[256 + t];
            __syncthreads();
            {
                float va[8] = {a0.x, a0.y, a0.z, a0.w, a1.x, a1.y, a1.z, a1.w};
                __bf16 h8[8], l8[8];
                #pragma unroll
                for (int j = 0; j < 8; j++) {
                    __bf16 h = (__bf16)va[j];
                    h8[j] = h;
                    l8[j] = (__bf16)(va[j] - (float)h);
                }
                *(bf16x8*)&As2[kq * 512 + rs * 8] = *(bf16x8*)&h8[0];
                *(bf16x8*)&As2[2048 + kq * 512 + rs * 8] = *(bf16x8*)&l8[0];
                ((float4*)Bs3)[t] = bv0;
                if (t < 128) ((float4*)Bs3)[256 + t] = bv1;
            }
            __syncthreads();
            bf16x8 ah, al, bh[3], blo[3];
            {
                int m = w * 16 + lr;
                ah = *(const bf16x8*)&As2[lk * 512 + m * 8];
                al = *(const bf16x8*)&As2[2048 + lk * 512 + m * 8];
            }
            #pragma unroll
            for (int nf = 0; nf < 3; nf++) {
                int n = nf * 16 + lr;
                bh[nf]  = *(const bf16x8*)&Bs3[lk * 384 + n * 8];
                blo[nf] = *(const bf16x8*)&Bs3[1536 + lk * 384 + n * 8];
            }
            #pragma unroll
            for (int nf = 0; nf < 3; nf++) {
                acc[o][nf] = __builtin_amdgcn_mfma_f32_16x16x32_bf16(ah, bh[nf],  acc[o][nf], 0, 0, 0);
                acc[o][nf] = __builtin_amdgcn_mfma_f32_16x16x32_bf16(ah, blo[nf], acc[o][nf], 0, 0, 0);
                acc[o][nf] = __builtin_amdgcn_mfma_f32_16x16x32_bf16(al, bh[nf],  acc[o][nf], 0, 0, 0);
            }
        }
    }
    // ---- combine
    float b32 = b3[32];
    if (lr == 0) {
        #pragma unroll
        for (int o = 0; o < 4; o++)
            #pragma unroll
            for (int r = 0; r < 4; r++)
                p3s[o][w * 16 + lk * 4 + r] = acc[o][2][r] + b32;
    }
    __syncthreads();
    float wgt[4][4];   // [r][o]
    #pragma unroll
    for (int r = 0; r < 4; r++) {
        int row = w * 16 + lk * 4 + r;
        float p0 = p3s[0][row], p1 = p3s[1][row], p2 = p3s[2][row], p3v = p3s[3][row];
        float mx = fmaxf(fmaxf(p0, p1), fmaxf(p2, p3v));
        float e0 = expf(p0 - mx), e1 = expf(p1 - mx);
        float e2 = expf(p2 - mx), e3 = expf(p3v - mx);
        float inv = 1.f / (e0 + e1 + e2 + e3);
        wgt[r][0] = e0 * inv; wgt[r][1] = e1 * inv;
        wgt[r][2] = e2 * inv; wgt[r][3] = e3 * inv;
    }
    int grow0 = row0 + bm0 + w * 16 + lk * 4;
    int b = grow0 >> 14, pix0 = grow0 & 16383;
    #pragma unroll
    for (int nf = 0; nf < 2; nf++) {
        int col = nf * 16 + lr;
        float bc = b3[col];
        float4 o4;
        float* po = (float*)&o4;
        #pragma unroll
        for (int r = 0; r < 4; r++) {
            float val = 0.f;
            #pragma unroll
            for (int o = 0; o < 4; o++)
                val = fmaf(acc[o][nf][r] + bc, wgt[r][o], val);
            po[r] = val;
        }
        *(float4*)&res[((size_t)b * 32 + col) * 16384 + pix0] = o4;
    }
}

// =========================================================================
static size_t align256(size_t x) { return (x + 255) & ~(size_t)255; }

static size_t region_bytes(int ch) {
    size_t region = align256((size_t)ch * 4 * NH1 * 4)
                  + align256((size_t)ch * 4 * NH2 * 4);
    size_t fftmin = 67108864 + 4096;   // inverse Zc(32MiB) + Yi(32MiB)
    if (region < fftmin) region = fftmin;
    return region;
}

static size_t plan_bytes(int ch) {
    size_t t = align256(region_bytes(ch));
    t += align256((size_t)Bn * 4096 * 128 * 4) * 2;      // featTM/TP
    t += align256((size_t)Bn * NPIX * 128 * 4) * 2;      // guideTM/TP
    t += align256((size_t)Bn * 32 * NPIX * 4);           // phares
    t += align256(131072) * 4;                           // w1f/w1g x2 br
    t += align256(262144) * 2;                           // w2t x2
    t += align256(24576) * 2;                            // w3t x2
    t += align256(2048) * 2;                             // relw x2
    t += align256((size_t)NPIX * 4 * 4);                 // idxb
    t += align256((size_t)NPIX * 4 * 8);                 // relb
    t += align256(32768) + align256(131072);             // A1f, A1g
    t += align256(65536) + align256(262144);             // A2f, A2g
    t += align256(262144) + align256(262144);            // iB1, iA2
    return t;
}

extern "C" void kernel_launch(void* const* d_in, const int* in_sizes, int n_in,
                              void* d_out, int out_size, void* d_ws, size_t ws_size,
                              hipStream_t stream) {
    const float* feat  = (const float*)d_in[0];
    const float* coord = (const float*)d_in[1];
    const float* guide = (const float*)d_in[2];
    const float* aw1 = (const float*)d_in[3];
    const float* ab1 = (const float*)d_in[4];
    const float* aw2 = (const float*)d_in[5];
    const float* ab2 = (const float*)d_in[6];
    const float* aw3 = (const float*)d_in[7];
    const float* ab3 = (const float*)d_in[8];
    const float* pw1 = (const float*)d_in[9];
    const float* pb1 = (const float*)d_in[10];
    const float* pw2 = (const float*)d_in[11];
    const float* pb2 = (const float*)d_in[12];
    const float* pw3 = (const float*)d_in[13];
    const float* pb3 = (const float*)d_in[14];
    float* out = (float*)d_out;

    int ch = 0;
    const int cands[3] = {16384, 8192, 4096};
    for (int i = 0; i < 3; i++)
        if (plan_bytes(cands[i]) <= ws_size) { ch = cands[i]; break; }
    if (ch == 0) return;
    const int nchk = (int)(ROWS / ch);

    char* ws = (char*)d_ws;
    size_t off = 0;
    auto alloc = [&](size_t bytes) -> void* {
        void* p = ws + off;
        off += align256(bytes);
        return p;
    };
    size_t region = region_bytes(ch);
    char*   rbase   = (char*)alloc(region);
    // region aliases: fwd Z1 (32MiB) | {H1c,H2c} | {Zc,Yi}
    float*  Z1      = (float*)rbase;
    float*  H1c     = (float*)rbase;
    float*  H2c     = (float*)(rbase + align256((size_t)ch * 4 * NH1 * 4));
    float*  Zc      = (float*)rbase;
    __bf16* Yi      = (__bf16*)(rbase + 33554432);
    float*  featTM  = (float*)alloc((size_t)Bn * 4096 * 128 * 4);
    float*  featTP  = (float*)alloc((size_t)Bn * 4096 * 128 * 4);
    float*  guideTM = (float*)alloc((size_t)Bn * NPIX * 128 * 4);
    float*  guideTP = (float*)alloc((size_t)Bn * NPIX * 128 * 4);
    float*  phares  = (float*)alloc((size_t)Bn * 32 * NPIX * 4);
    float*  magres  = out;   // alias: consumed by k_prep_zc before out written
    __bf16* w1fa    = (__bf16*)alloc(131072);
    __bf16* w1ga    = (__bf16*)alloc(131072);
    __bf16* w1fp    = (__bf16*)alloc(131072);
    __bf16* w1gp    = (__bf16*)alloc(131072);
    __bf16* w2ta    = (__bf16*)alloc(262144);
    __bf16* w2tp    = (__bf16*)alloc(262144);
    __bf16* w3ta    = (__bf16*)alloc(24576);
    __bf16* w3tp    = (__bf16*)alloc(24576);
    float2* relwa   = (float2*)alloc(2048);
    float2* relwp   = (float2*)alloc(2048);
    int*    idxb    = (int*)alloc((size_t)NPIX * 4 * 4);
    float2* relb    = (float2*)alloc((size_t)NPIX * 4 * 8);
    __bf16* A1f     = (__bf16*)alloc(32768);
    __bf16* A1g     = (__bf16*)alloc(131072);
    __bf16* A2f     = (__bf16*)alloc(65536);
    __bf16* A2g     = (__bf16*)alloc(262144);
    __bf16* iB1     = (__bf16*)alloc(262144);
    __bf16* iA2     = (__bf16*)alloc(262144);

    // ---- prep
    k_prep_w1split<<<(256 * 256 + TPB - 1) / TPB, TPB, 0, stream>>>(aw1, w1fa, w1ga, relwa);
    k_prep_w1split<<<(256 * 256 + TPB - 1) / TPB, TPB, 0, stream>>>(pw1, w1fp, w1gp, relwp);
    k_prep_w2<<<(256 * 128 + TPB - 1) / TPB, TPB, 0, stream>>>(aw2, w2ta);
    k_prep_w2<<<(256 * 128 + TPB - 1) / TPB, TPB, 0, stream>>>(pw2, w2tp);
    k_prep_w3<<<(128 * 48 + TPB - 1) / TPB, TPB, 0, stream>>>(aw3, w3ta);
    k_prep_w3<<<(128 * 48 + TPB - 1) / TPB, TPB, 0, stream>>>(pw3, w3tp);
    k_meta<<<(NPIX * 4 + TPB - 1) / TPB, TPB, 0, stream>>>(coord, idxb, relb);
    k_prep_fftA1<<<(2 * 64 * 64 + TPB - 1) / TPB, TPB, 0, stream>>>(64, A1f);
    k_prep_fftA1<<<(2 * 128 * 128 + TPB - 1) / TPB, TPB, 0, stream>>>(128, A1g);
    k_prep_fftmat<<<(128 * 128 + TPB - 1) / TPB, TPB, 0, stream>>>(1, 64, A2f);
    k_prep_fftmat<<<(256 * 256 + TPB - 1) / TPB, TPB, 0, stream>>>(1, 128, A2g);
    k_prep_fftmat<<<(256 * 256 + TPB - 1) / TPB, TPB, 0, stream>>>(2, 128, iB1);
    k_prep_fftmat<<<(256 * 256 + TPB - 1) / TPB, TPB, 0, stream>>>(3, 128, iA2);

    // ---- forward FFT feat: all 8 b at once (Z1 = 16 MiB)
    k_fft1<64><<<dim3(512, 1), TPB, 0, stream>>>(feat, A1f, Z1, 0);
    k_fft2<64><<<dim3(512, 1), TPB, 0, stream>>>(A2f, Z1, featTM, featTP, 0);
    // ---- forward FFT guide: 2 b per sweep (Z1 = 32 MiB)
    for (int bp = 0; bp < 4; bp++) {
        int b0 = bp * 2;
        k_fft1<128><<<dim3(256, 2), TPB, 0, stream>>>(guide, A1g, Z1, b0);
        k_fft2<128><<<dim3(256, 2), TPB, 0, stream>>>(A2g, Z1, guideTM, guideTP, b0);
    }

    // ---- two MLP branches, row-chunked
    for (int br = 0; br < 2; br++) {
        const float*  fT   = br ? featTP  : featTM;
        const float*  gT   = br ? guideTP : guideTM;
        const __bf16* w1f  = br ? w1fp : w1fa;
        const __bf16* w1g  = br ? w1gp : w1ga;
        const float2* relw = br ? relwp : relwa;
        const float*  b1   = br ? pb1 : ab1;
        const __bf16* w2t  = br ? w2tp : w2ta;
        const float*  b2   = br ? pb2 : ab2;
        const __bf16* w3t  = br ? w3tp : w3ta;
        const float*  b3   = br ? pb3 : ab3;
        float* resb = br ? phares : magres;
        for (int c = 0; c < nchk; c++) {
            int row0 = c * ch;
            k_gemm1f<<<dim3(ch / 64, 2), TPB, 0, stream>>>(
                fT, gT, idxb, relb, row0, ch, w1f, w1g, relw, b1, H1c);
            k_gemm2_mfma<<<dim3(ch / 128, 1, 4), TPB, 0, stream>>>(
                H1c, w2t, b2, H2c, ch);
            k_g3c<<<dim3(ch / 64), TPB, 0, stream>>>(
                H2c, w3t, b3, row0, ch, resb);
        }
    }

    // ---- inverse FFT (256 imgs 128x128) + abs (legacy MFMA path)
    k_prep_zc<<<(256 * NPIX) / TPB, TPB, 0, stream>>>(magres, phares, Zc);
    k_fft_p1<256, 128, 128><<<dim3(256, 2), TPB, 0, stream>>>(Zc, iB1, Yi);
    k_fft_p2<128, 128, 2><<<dim3(256, 2), TPB, 0, stream>>>(iA2, Yi, out, nullptr);
}